// Round 2
// baseline (1346.698 us; speedup 1.0000x reference)
//
#include <hip/hip_runtime.h>

// RWKV7 attention block, MI355X/gfx950.
// Shapes: B=1, T=1024, C=2048, H=32, N=64. All inputs/outputs f32 per reference.
// Big GEMMs use split-bf16 MFMA (hi+lo, 3 MFMA terms) for ~f32 accuracy at
// MFMA rates; everything else f32 VALU.

#define T_ 1024
#define C_ 2048
#define H_ 32
#define N_ 64

using short8  = __attribute__((ext_vector_type(8))) short;   // 8 bf16 (4 VGPRs)
using floatx4 = __attribute__((ext_vector_type(4))) float;   // 4 f32 acc

struct __align__(8) US4 { unsigned short a, b, c, d; };

__device__ __forceinline__ unsigned short f2bf(float f) {
    unsigned u = __float_as_uint(f);
    u += 0x7fffu + ((u >> 16) & 1u);   // round-to-nearest-even
    return (unsigned short)(u >> 16);
}
__device__ __forceinline__ float bf2f(unsigned short h) {
    return __uint_as_float(((unsigned)h) << 16);
}
__device__ __forceinline__ void split_bf(float x, unsigned short& h, unsigned short& l) {
    h = f2bf(x);
    l = f2bf(x - bf2f(h));   // residual exact (leading bits cancel), then RNE
}

// ---------------------------------------------------------------------------
// Transpose + convert: W[k][n] f32 -> hi/lo bf16 WT[n][k] (z selects weight)
// ---------------------------------------------------------------------------
__global__ __launch_bounds__(256) void k_tr(
    const float* __restrict__ W0, const float* __restrict__ W1,
    const float* __restrict__ W2,
    unsigned short* __restrict__ H0, unsigned short* __restrict__ L0,
    unsigned short* __restrict__ H1, unsigned short* __restrict__ L1,
    unsigned short* __restrict__ H2, unsigned short* __restrict__ L2)
{
    const int z = blockIdx.z;
    const float* S = (z == 0) ? W0 : (z == 1) ? W1 : W2;
    unsigned short* DH = (z == 0) ? H0 : (z == 1) ? H1 : H2;
    unsigned short* DL = (z == 0) ? L0 : (z == 1) ? L1 : L2;
    const int nb = blockIdx.x * 64, kb = blockIdx.y * 64;
    __shared__ __align__(16) float tile[64][65];
    const int tr = threadIdx.x >> 4, tc4 = (threadIdx.x & 15) * 4;
#pragma unroll
    for (int p = 0; p < 4; ++p) {
        int row = p * 16 + tr;
        float4 v = *(const float4*)&S[(size_t)(kb + row) * C_ + nb + tc4];
        tile[row][tc4 + 0] = v.x; tile[row][tc4 + 1] = v.y;
        tile[row][tc4 + 2] = v.z; tile[row][tc4 + 3] = v.w;
    }
    __syncthreads();
#pragma unroll
    for (int p = 0; p < 4; ++p) {
        int n = p * 16 + tr;
        US4 uh, ul;
        split_bf(tile[tc4 + 0][n], uh.a, ul.a);
        split_bf(tile[tc4 + 1][n], uh.b, ul.b);
        split_bf(tile[tc4 + 2][n], uh.c, ul.c);
        split_bf(tile[tc4 + 3][n], uh.d, ul.d);
        *(US4*)&DH[(size_t)(nb + n) * C_ + kb + tc4] = uh;
        *(US4*)&DL[(size_t)(nb + n) * C_ + kb + tc4] = ul;
    }
}

// ---------------------------------------------------------------------------
// Stage-1 small projections: Y = [tanh](X @ W1). t-tile 8, 256 thr.
// mode 0: X=xxx(on-the-fly shift-mix of hidden), W=maa_w1[2048,128] -> m1, tanh
// mode 1: X=xrg, gate_w1[2048,128] -> g1, tanh
// mode 2: X=xwa, cols 0-63 decay_w1(tanh) | 64-79 aaa_w1 | 80-95 ma_w1 -> wam[T,96]
// mode 3: X=xk,  cols 0-15 kkk_w1(tanh) | 16-31 mk_w1 -> km[T,32]
// ---------------------------------------------------------------------------
__global__ __launch_bounds__(256) void k_small1(
    int mode_base,
    const float* __restrict__ hidden, const float* __restrict__ maa_x,
    const float* __restrict__ maa_w1,
    const float* __restrict__ xrg, const float* __restrict__ gate_w1,
    const float* __restrict__ xwa, const float* __restrict__ decay_w1,
    const float* __restrict__ aaa_w1, const float* __restrict__ ma_w1,
    const float* __restrict__ xk, const float* __restrict__ kkk_w1,
    const float* __restrict__ mk_w1,
    float* __restrict__ m1, float* __restrict__ g1,
    float* __restrict__ wam, float* __restrict__ km)
{
    const int mode = mode_base + blockIdx.z;
    const int t0 = blockIdx.x * 8;
    const int tid = threadIdx.x;
    const int n = tid & 127, rh = tid >> 7;

    const float* X = hidden;
    const float* Wp = maa_w1;   // safe defaults
    float* Yp = m1;
    int wstride = 128, ystride = 128;
    bool dotanh = true, act = true;

    if (mode == 0) { X = hidden; Wp = maa_w1 + n; Yp = m1 + n; }
    else if (mode == 1) { X = xrg; Wp = gate_w1 + n; Yp = g1 + n; }
    else if (mode == 2) {
        X = xwa; ystride = 96; Yp = wam + n;
        if (n < 64)      { Wp = decay_w1 + n;      wstride = 64; dotanh = true; }
        else if (n < 80) { Wp = aaa_w1 + (n - 64); wstride = 16; dotanh = false; }
        else if (n < 96) { Wp = ma_w1 + (n - 80);  wstride = 16; dotanh = false; }
        else act = false;
    } else {
        X = xk; ystride = 32; Yp = km + n;
        if (n < 16)      { Wp = kkk_w1 + n;        wstride = 16; dotanh = true; }
        else if (n < 32) { Wp = mk_w1 + (n - 16);  wstride = 16; dotanh = false; }
        else act = false;
    }

    __shared__ __align__(16) float xs[8][64];
    float acc[4] = {0.f, 0.f, 0.f, 0.f};

    for (int kc = 0; kc < C_; kc += 64) {
        {
            int r = tid >> 5, c2 = (tid & 31) * 2;
            const float* xb = X + (size_t)(t0 + r) * C_ + kc + c2;
            float2 xv = *(const float2*)xb;
            if (mode == 0) {
                float2 xp = make_float2(0.f, 0.f);
                if (t0 + r > 0) xp = *(const float2*)(xb - C_);
                float2 mx = *(const float2*)&maa_x[kc + c2];
                xv.x = xv.x + (xp.x - xv.x) * mx.x;
                xv.y = xv.y + (xp.y - xv.y) * mx.y;
            }
            *(float2*)&xs[r][c2] = xv;
        }
        __syncthreads();
        if (act) {
            for (int kk = 0; kk < 64; kk += 4) {
                float w0 = Wp[(size_t)(kc + kk + 0) * wstride];
                float w1 = Wp[(size_t)(kc + kk + 1) * wstride];
                float w2 = Wp[(size_t)(kc + kk + 2) * wstride];
                float w3 = Wp[(size_t)(kc + kk + 3) * wstride];
#pragma unroll
                for (int rr = 0; rr < 4; ++rr) {
                    float4 xr = *(float4*)&xs[rh * 4 + rr][kk];
                    acc[rr] = fmaf(xr.x, w0, fmaf(xr.y, w1, fmaf(xr.z, w2, fmaf(xr.w, w3, acc[rr]))));
                }
            }
        }
        __syncthreads();
    }
    if (act) {
#pragma unroll
        for (int rr = 0; rr < 4; ++rr) {
            float v = acc[rr];
            if (dotanh) v = tanhf(v);
            Yp[(size_t)(t0 + rh * 4 + rr) * ystride] = v;
        }
    }
}

// ---------------------------------------------------------------------------
// xmix: mix = einsum(m1[T,4,32], maa_w2[4,32,C]); xrg/xwa/xk/xv from hidden
// ---------------------------------------------------------------------------
__global__ __launch_bounds__(256) void k_xmix(
    const float* __restrict__ X, const float* __restrict__ m1,
    const float* __restrict__ w2,
    const float* __restrict__ mrg, const float* __restrict__ mwa,
    const float* __restrict__ mk, const float* __restrict__ mv,
    float* __restrict__ xrg, float* __restrict__ xwa,
    float* __restrict__ xk, float* __restrict__ xv)
{
    const int tid = threadIdx.x;
    const int c = blockIdx.x * 256 + tid;
    const int t0 = blockIdx.y * 16;
    __shared__ __align__(16) float m1s[16][128];
#pragma unroll
    for (int p = 0; p < 2; ++p) {
        int id = tid + p * 256;
        int r = id >> 5, c4 = (id & 31) * 4;
        *(float4*)&m1s[r][c4] = *(const float4*)&m1[(size_t)(t0 + r) * 128 + c4];
    }
    __syncthreads();
    float a0[16], a1[16], a2[16], a3[16];
#pragma unroll
    for (int t = 0; t < 16; ++t) { a0[t] = 0.f; a1[t] = 0.f; a2[t] = 0.f; a3[t] = 0.f; }
    for (int d = 0; d < 32; ++d) {
        float w0 = w2[(size_t)(0 * 32 + d) * C_ + c];
        float w1 = w2[(size_t)(1 * 32 + d) * C_ + c];
        float w2v = w2[(size_t)(2 * 32 + d) * C_ + c];
        float w3 = w2[(size_t)(3 * 32 + d) * C_ + c];
#pragma unroll
        for (int t = 0; t < 16; ++t) {
            a0[t] = fmaf(m1s[t][d],      w0,  a0[t]);
            a1[t] = fmaf(m1s[t][32 + d], w1,  a1[t]);
            a2[t] = fmaf(m1s[t][64 + d], w2v, a2[t]);
            a3[t] = fmaf(m1s[t][96 + d], w3,  a3[t]);
        }
    }
    float vrg = mrg[c], vwa = mwa[c], vk = mk[c], vv = mv[c];
    float prev = (t0 > 0) ? X[(size_t)(t0 - 1) * C_ + c] : 0.0f;
    for (int t = 0; t < 16; ++t) {
        size_t idx = (size_t)(t0 + t) * C_ + c;
        float cur = X[idx];
        float dx = prev - cur;
        xrg[idx] = cur + dx * (vrg + a0[t]);
        xwa[idx] = cur + dx * (vwa + a1[t]);
        xk[idx]  = cur + dx * (vk  + a2[t]);
        xv[idx]  = cur + dx * (vv  + a3[t]);
        prev = cur;
    }
}

// ---------------------------------------------------------------------------
// Split-bf16 MFMA GEMM: C[1024,2048] = A[1024,2048](f32) * W, W given as
// transposed hi/lo bf16 WT[n][k]. A split into hi/lo on the fly.
// acc += aH*bH + aL*bH + aH*bL  (lo*lo dropped, ~2^-18 rel).
// BM=BN=128, BK=32, 256 thr (4 waves, 2x2), 4x4 16x16x32 tiles/wave.
// ---------------------------------------------------------------------------
__global__ __launch_bounds__(256) void k_gemm(
    const float* __restrict__ A0, const unsigned short* __restrict__ BH0,
    const unsigned short* __restrict__ BL0, float* __restrict__ C0,
    const float* __restrict__ A1, const unsigned short* __restrict__ BH1,
    const unsigned short* __restrict__ BL1, float* __restrict__ C1,
    const float* __restrict__ A2, const unsigned short* __restrict__ BH2,
    const unsigned short* __restrict__ BL2, float* __restrict__ C2)
{
    const int z = blockIdx.z;
    const float* A = (z == 0) ? A0 : (z == 1) ? A1 : A2;
    const unsigned short* BH = (z == 0) ? BH0 : (z == 1) ? BH1 : BH2;
    const unsigned short* BL = (z == 0) ? BL0 : (z == 1) ? BL1 : BL2;
    float* C = (z == 0) ? C0 : (z == 1) ? C1 : C2;
    const int mtile = blockIdx.y * 128;
    const int ntile = blockIdx.x * 128;
    const int tid = threadIdx.x;
    __shared__ __align__(16) unsigned short AsH[128 * 40];  // row stride 40 (pad)
    __shared__ __align__(16) unsigned short AsL[128 * 40];
    __shared__ __align__(16) unsigned short BsH[128 * 40];
    __shared__ __align__(16) unsigned short BsL[128 * 40];
    const int lane = tid & 63;
    const int wvid = tid >> 6;
    const int wm = wvid >> 1, wn = wvid & 1;
    const int r16 = lane & 15, q = lane >> 4;

    floatx4 acc[4][4];
#pragma unroll
    for (int i = 0; i < 4; ++i)
#pragma unroll
        for (int j = 0; j < 4; ++j) { floatx4 zv = {0.f, 0.f, 0.f, 0.f}; acc[i][j] = zv; }

    const int srow = tid >> 1, shalf = tid & 1;
    const float* ag = A + (size_t)(mtile + srow) * C_ + shalf * 16;
    const unsigned short* bhg = BH + (size_t)(ntile + srow) * C_ + shalf * 16;
    const unsigned short* blg = BL + (size_t)(ntile + srow) * C_ + shalf * 16;
    unsigned short* ahw = &AsH[srow * 40 + shalf * 16];
    unsigned short* alw = &AsL[srow * 40 + shalf * 16];
    unsigned short* bhw = &BsH[srow * 40 + shalf * 16];
    unsigned short* blw = &BsL[srow * 40 + shalf * 16];

    for (int kc = 0; kc < C_; kc += 32) {
        float4 f0 = *(const float4*)(ag + kc + 0);
        float4 f1 = *(const float4*)(ag + kc + 4);
        float4 f2 = *(const float4*)(ag + kc + 8);
        float4 f3 = *(const float4*)(ag + kc + 12);
        short8 p0h, p0l, p1h, p1l;
        unsigned short h, l;
        split_bf(f0.x, h, l); p0h[0] = (short)h; p0l[0] = (short)l;
        split_bf(f0.y, h, l); p0h[1] = (short)h; p0l[1] = (short)l;
        split_bf(f0.z, h, l); p0h[2] = (short)h; p0l[2] = (short)l;
        split_bf(f0.w, h, l); p0h[3] = (short)h; p0l[3] = (short)l;
        split_bf(f1.x, h, l); p0h[4] = (short)h; p0l[4] = (short)l;
        split_bf(f1.y, h, l); p0h[5] = (short)h; p0l[5] = (short)l;
        split_bf(f1.z, h, l); p0h[6] = (short)h; p0l[6] = (short)l;
        split_bf(f1.w, h, l); p0h[7] = (short)h; p0l[7] = (short)l;
        split_bf(f2.x, h, l); p1h[0] = (short)h; p1l[0] = (short)l;
        split_bf(f2.y, h, l); p1h[1] = (short)h; p1l[1] = (short)l;
        split_bf(f2.z, h, l); p1h[2] = (short)h; p1l[2] = (short)l;
        split_bf(f2.w, h, l); p1h[3] = (short)h; p1l[3] = (short)l;
        split_bf(f3.x, h, l); p1h[4] = (short)h; p1l[4] = (short)l;
        split_bf(f3.y, h, l); p1h[5] = (short)h; p1l[5] = (short)l;
        split_bf(f3.z, h, l); p1h[6] = (short)h; p1l[6] = (short)l;
        split_bf(f3.w, h, l); p1h[7] = (short)h; p1l[7] = (short)l;
        short8 bh0 = *(const short8*)(bhg + kc);
        short8 bh1 = *(const short8*)(bhg + kc + 8);
        short8 bl0 = *(const short8*)(blg + kc);
        short8 bl1 = *(const short8*)(blg + kc + 8);
        *(short8*)ahw = p0h; *(short8*)(ahw + 8) = p1h;
        *(short8*)alw = p0l; *(short8*)(alw + 8) = p1l;
        *(short8*)bhw = bh0; *(short8*)(bhw + 8) = bh1;
        *(short8*)blw = bl0; *(short8*)(blw + 8) = bl1;
        __syncthreads();

        short8 aH[4], aL[4], bHf[4], bLf[4];
#pragma unroll
        for (int i = 0; i < 4; ++i) {
            int ro = (wm * 64 + i * 16 + r16) * 40 + q * 8;
            aH[i] = *(const short8*)&AsH[ro];
            aL[i] = *(const short8*)&AsL[ro];
        }
#pragma unroll
        for (int j = 0; j < 4; ++j) {
            int ro = (wn * 64 + j * 16 + r16) * 40 + q * 8;
            bHf[j] = *(const short8*)&BsH[ro];
            bLf[j] = *(const short8*)&BsL[ro];
        }
#pragma unroll
        for (int i = 0; i < 4; ++i)
#pragma unroll
            for (int j = 0; j < 4; ++j) {
                acc[i][j] = __builtin_amdgcn_mfma_f32_16x16x32_bf16(aH[i], bHf[j], acc[i][j], 0, 0, 0);
                acc[i][j] = __builtin_amdgcn_mfma_f32_16x16x32_bf16(aL[i], bHf[j], acc[i][j], 0, 0, 0);
                acc[i][j] = __builtin_amdgcn_mfma_f32_16x16x32_bf16(aH[i], bLf[j], acc[i][j], 0, 0, 0);
            }
        __syncthreads();
    }
    // C/D layout: col = lane&15, row = (lane>>4)*4 + reg
#pragma unroll
    for (int i = 0; i < 4; ++i)
#pragma unroll
        for (int j = 0; j < 4; ++j)
#pragma unroll
            for (int e = 0; e < 4; ++e) {
                int row = mtile + wm * 64 + i * 16 + q * 4 + e;
                int col = ntile + wn * 64 + j * 16 + r16;
                C[(size_t)row * C_ + col] = acc[i][j][e];
            }
}

// ---------------------------------------------------------------------------
// Fused stage-2: w, a, ma, mk, kk_unnorm, k_final (in place over k0)
// ---------------------------------------------------------------------------
__global__ __launch_bounds__(256) void k_fuse(
    const float* __restrict__ wam, const float* __restrict__ km,
    float* __restrict__ K0,
    const float* __restrict__ decay_w2, const float* __restrict__ aaa_w2,
    const float* __restrict__ ma_w2, const float* __restrict__ kkk_w2,
    const float* __restrict__ mk_w2,
    const float* __restrict__ tdecay, const float* __restrict__ aaaaa,
    const float* __restrict__ misc_a, const float* __restrict__ misc_k,
    float* __restrict__ Wout, float* __restrict__ KKout, float* __restrict__ Aout)
{
    const int tid = threadIdx.x;
    const int c = blockIdx.x * 256 + tid;
    const int t0 = blockIdx.y * 16;
    __shared__ __align__(16) float wsS[16][96];
    __shared__ __align__(16) float ksS[16][32];
    for (int id = tid; id < 16 * 24; id += 256) {
        int r = id / 24, c4 = (id % 24) * 4;
        *(float4*)&wsS[r][c4] = *(const float4*)&wam[(size_t)(t0 + r) * 96 + c4];
    }
    for (int id = tid; id < 16 * 8; id += 256) {
        int r = id / 8, c4 = (id % 8) * 4;
        *(float4*)&ksS[r][c4] = *(const float4*)&km[(size_t)(t0 + r) * 32 + c4];
    }
    __syncthreads();
    float accW[16], accA[16], accMA[16], accKK[16], accMK[16];
#pragma unroll
    for (int r = 0; r < 16; ++r) { accW[r] = 0.f; accA[r] = 0.f; accMA[r] = 0.f; accKK[r] = 0.f; accMK[r] = 0.f; }
    for (int j = 0; j < 64; ++j) {
        float w = decay_w2[(size_t)j * C_ + c];
#pragma unroll
        for (int r = 0; r < 16; ++r) accW[r] = fmaf(wsS[r][j], w, accW[r]);
    }
    for (int j = 0; j < 16; ++j) {
        float wa = aaa_w2[(size_t)j * C_ + c];
        float wm = ma_w2[(size_t)j * C_ + c];
        float wk = kkk_w2[(size_t)j * C_ + c];
        float wq = mk_w2[(size_t)j * C_ + c];
#pragma unroll
        for (int r = 0; r < 16; ++r) {
            accA[r]  = fmaf(wsS[r][64 + j], wa, accA[r]);
            accMA[r] = fmaf(wsS[r][80 + j], wm, accMA[r]);
            accKK[r] = fmaf(ksS[r][j],      wk, accKK[r]);
            accMK[r] = fmaf(ksS[r][16 + j], wq, accMK[r]);
        }
    }
    float td = tdecay[c], aa = aaaaa[c], mia = misc_a[c], mik = misc_k[c];
    for (int r = 0; r < 16; ++r) {
        size_t idx = (size_t)(t0 + r) * C_ + c;
        float wraw = td + accW[r];
        float w = -logf(1.0f + __expf(-wraw)) - 0.5f;   // -softplus(-x) - 0.5
        float a  = 1.0f / (1.0f + __expf(-(aa  + accA[r])));
        float mav = 1.0f / (1.0f + __expf(-(mia + accMA[r])));
        float mkv = 1.0f / (1.0f + __expf(-(mik + accMK[r])));
        float k0 = K0[idx];
        Wout[idx]  = w;
        KKout[idx] = k0 + accKK[r];
        K0[idx]    = k0 * (mav + a * (1.0f - mav)) * __expf(fminf(w * mkv, 0.0f));
        Aout[idx]  = a;
    }
}

// ---------------------------------------------------------------------------
// kk L2-normalize per (t,head); b = kk_hat * a_sig written over a_sig.
// ---------------------------------------------------------------------------
__global__ __launch_bounds__(256) void k_kknorm(float* __restrict__ KK, float* __restrict__ Ab)
{
    const int t = blockIdx.y;
    const int c = blockIdx.x * 256 + threadIdx.x;
    const size_t idx = (size_t)t * C_ + c;
    float kv = KK[idx];
    float ss = kv * kv;
#pragma unroll
    for (int off = 1; off < 64; off <<= 1) ss += __shfl_xor(ss, off, 64);
    float scale = 1.0f / fmaxf(sqrtf(ss), 1e-12f);
    float kn = kv * scale;
    KK[idx] = kn;
    Ab[idx] = kn * Ab[idx];
}

// ---------------------------------------------------------------------------
// Gate stage-2: G = g1[T,128] @ gate_w2[128,2048]
// ---------------------------------------------------------------------------
__global__ __launch_bounds__(256) void k_gate2(
    const float* __restrict__ g1, const float* __restrict__ w2, float* __restrict__ G)
{
    const int tid = threadIdx.x;
    const int c = blockIdx.x * 256 + tid;
    const int t0 = blockIdx.y * 16;
    __shared__ __align__(16) float gs[16][128];
#pragma unroll
    for (int p = 0; p < 2; ++p) {
        int id = tid + p * 256;
        int r = id >> 5, c4 = (id & 31) * 4;
        *(float4*)&gs[r][c4] = *(const float4*)&g1[(size_t)(t0 + r) * 128 + c4];
    }
    __syncthreads();
    float acc[16];
#pragma unroll
    for (int r = 0; r < 16; ++r) acc[r] = 0.f;
    for (int j = 0; j < 128; ++j) {
        float w = w2[(size_t)j * C_ + c];
#pragma unroll
        for (int r = 0; r < 16; ++r) acc[r] = fmaf(gs[r][j], w, acc[r]);
    }
    for (int r = 0; r < 16; ++r) G[(size_t)(t0 + r) * C_ + c] = acc[r];
}

// ---------------------------------------------------------------------------
// WKV7 scan. 4 blocks/head (rows split: rows independent given shared
// per-step j-vectors). 256 thr: wave covers 4 rows x 16 j-groups (js=4).
// 16-step chunks staged in LDS; dec=exp(w), a=-kk, b staged pre-derived.
// ---------------------------------------------------------------------------
__global__ __launch_bounds__(256) void k_wkv(
    const float* __restrict__ R, const float* __restrict__ Wd,
    const float* __restrict__ K, const float* __restrict__ V,
    const float* __restrict__ KK, const float* __restrict__ Bb,
    float* __restrict__ Y)
{
    const int tid = threadIdx.x;
    const int h = blockIdx.x >> 2;
    const int rg = blockIdx.x & 3;
    const int c0 = h * 64;
    const int wv = tid >> 6, lane = tid & 63;
    const int irow = rg * 16 + wv * 4 + (lane >> 4);
    const int jg = lane & 15;
    __shared__ __align__(16) float rS[16][64], dS[16][64], kS[16][64],
                                   vS[16][64], aS[16][64], bS[16][64], oS[16][64];
    float4 s = make_float4(0.f, 0.f, 0.f, 0.f);
    const int tloc = tid >> 4, j4 = (tid & 15) * 4;

    for (int tc = 0; tc < T_; tc += 16) {
        size_t gi = (size_t)(tc + tloc) * C_ + c0 + j4;
        *(float4*)&rS[tloc][j4] = *(const float4*)&R[gi];
        float4 w4 = *(const float4*)&Wd[gi];
        float4 d4;
        d4.x = __expf(w4.x); d4.y = __expf(w4.y); d4.z = __expf(w4.z); d4.w = __expf(w4.w);
        *(float4*)&dS[tloc][j4] = d4;
        *(float4*)&kS[tloc][j4] = *(const float4*)&K[gi];
        *(float4*)&vS[tloc][j4] = *(const float4*)&V[gi];
        float4 kk4 = *(const float4*)&KK[gi];
        float4 a4 = make_float4(-kk4.x, -kk4.y, -kk4.z, -kk4.w);
        *(float4*)&aS[tloc][j4] = a4;
        *(float4*)&bS[tloc][j4] = *(const float4*)&Bb[gi];
        __syncthreads();

#pragma unroll
        for (int tt = 0; tt < 16; ++tt) {
            float4 a = *(float4*)&aS[tt][jg * 4];
            float sa = s.x * a.x + s.y * a.y + s.z * a.z + s.w * a.w;
            sa += __shfl_xor(sa, 1, 64); sa += __shfl_xor(sa, 2, 64);
            sa += __shfl_xor(sa, 4, 64); sa += __shfl_xor(sa, 8, 64);
            float vi = vS[tt][irow];
            float4 d = *(float4*)&dS[tt][jg * 4];
            float4 b = *(float4*)&bS[tt][jg * 4];
            float4 k = *(float4*)&kS[tt][jg * 4];
            s.x = fmaf(s.x, d.x, fmaf(sa, b.x, vi * k.x));
            s.y = fmaf(s.y, d.y, fmaf(sa, b.y, vi * k.y));
            s.z = fmaf(s.z, d.z, fmaf(sa, b.z, vi * k.z));
            s.w = fmaf(s.w, d.w, fmaf(sa, b.w, vi * k.w));
            float4 r = *(float4*)&rS[tt][jg * 4];
            float o = s.x * r.x + s.y * r.y + s.z * r.z + s.w * r.w;
            o += __shfl_xor(o, 1, 64); o += __shfl_xor(o, 2, 64);
            o += __shfl_xor(o, 4, 64); o += __shfl_xor(o, 8, 64);
            if (jg == 0) oS[tt][irow] = o;
        }
        __syncthreads();
        Y[(size_t)(tc + tloc) * C_ + c0 + rg * 16 + (tid & 15)] = oS[tloc][rg * 16 + (tid & 15)];
    }
}

// ---------------------------------------------------------------------------
// GroupNorm(y) * ln_w + ln_b, + bonus, * gate (in place over Y)
// ---------------------------------------------------------------------------
__global__ __launch_bounds__(256) void k_gn(
    float* __restrict__ Y, const float* __restrict__ R, const float* __restrict__ K,
    const float* __restrict__ V, const float* __restrict__ G,
    const float* __restrict__ faaaa, const float* __restrict__ lnw,
    const float* __restrict__ lnb)
{
    const int t = blockIdx.y;
    const int c = blockIdx.x * 256 + threadIdx.x;
    const size_t idx = (size_t)t * C_ + c;
    float y = Y[idx];
    float s1 = y, s2 = y * y;
#pragma unroll
    for (int off = 1; off < 64; off <<= 1) {
        s1 += __shfl_xor(s1, off, 64);
        s2 += __shfl_xor(s2, off, 64);
    }
    float mu = s1 * (1.0f / 64.0f);
    float var = s2 * (1.0f / 64.0f) - mu * mu;
    float gn = (y - mu) * rsqrtf(var + 0.00064f) * lnw[c] + lnb[c];
    float p = R[idx] * K[idx] * faaaa[c];
#pragma unroll
    for (int off = 1; off < 64; off <<= 1) p += __shfl_xor(p, off, 64);
    float y2 = gn + p * V[idx];
    Y[idx] = y2 * G[idx];
}

// ---------------------------------------------------------------------------
extern "C" void kernel_launch(void* const* d_in, const int* in_sizes, int n_in,
                              void* d_out, int out_size, void* d_ws, size_t ws_size,
                              hipStream_t stream)
{
    (void)in_sizes; (void)n_in; (void)out_size; (void)ws_size;
    const float* hidden   = (const float*)d_in[0];
    const float* Wq       = (const float*)d_in[1];
    const float* Wk       = (const float*)d_in[2];
    const float* Wv       = (const float*)d_in[3];
    const float* Wo       = (const float*)d_in[4];
    const float* maa_x    = (const float*)d_in[5];
    const float* maa_rg   = (const float*)d_in[6];
    const float* maa_wa   = (const float*)d_in[7];
    const float* maa_k    = (const float*)d_in[8];
    const float* maa_v    = (const float*)d_in[9];
    const float* maa_w1   = (const float*)d_in[10];
    const float* maa_w2   = (const float*)d_in[11];
    const float* tdecay   = (const float*)d_in[12];
    const float* decay_w1 = (const float*)d_in[13];
    const float* decay_w2 = (const float*)d_in[14];
    const float* aaaaa    = (const float*)d_in[15];
    const float* aaa_w1   = (const float*)d_in[16];
    const float* aaa_w2   = (const float*)d_in[17];
    const float* kkk_w1   = (const float*)d_in[18];
    const float* kkk_w2   = (const float*)d_in[19];
    const float* gate_w1  = (const float*)d_in[20];
    const float* gate_w2  = (const float*)d_in[21];
    const float* misc_a   = (const float*)d_in[22];
    const float* ma_w1    = (const float*)d_in[23];
    const float* ma_w2    = (const float*)d_in[24];
    const float* misc_k   = (const float*)d_in[25];
    const float* mk_w1    = (const float*)d_in[26];
    const float* mk_w2    = (const float*)d_in[27];
    const float* faaaa    = (const float*)d_in[28];
    const float* lnw      = (const float*)d_in[29];
    const float* lnb      = (const float*)d_in[30];

    float* ws = (float*)d_ws;
    const size_t TC = (size_t)T_ * C_;
    // Buffer plan (8 x TC f32):
    //   S0: xrg -> y -> y*g      S1: xwa -> g       S2: xk -> a_sig -> b
    //   S3: xv -> kk             S4: r              S5: w
    //   S6: k0 -> k_final        S7: v
    float* S0 = ws + 0 * TC;
    float* S1 = ws + 1 * TC;
    float* S2 = ws + 2 * TC;
    float* S3 = ws + 3 * TC;
    float* S4 = ws + 4 * TC;
    float* S5 = ws + 5 * TC;
    float* S6 = ws + 6 * TC;
    float* S7 = ws + 7 * TC;
    float* m1  = ws + 8 * TC;              // [T,128]
    float* g1  = m1 + (size_t)T_ * 128;    // [T,128]
    float* wam = g1 + (size_t)T_ * 128;    // [T,96]
    float* km  = wam + (size_t)T_ * 96;    // [T,32]
    // 6 bf16 C*C buffers: q/k/v hi+lo; Wo re-transposed into slot 0 after rkv GEMM
    unsigned short* WH0 = (unsigned short*)(km + (size_t)T_ * 32);
    unsigned short* WL0 = WH0 + (size_t)C_ * C_;
    unsigned short* WH1 = WL0 + (size_t)C_ * C_;
    unsigned short* WL1 = WH1 + (size_t)C_ * C_;
    unsigned short* WH2 = WL1 + (size_t)C_ * C_;
    unsigned short* WL2 = WH2 + (size_t)C_ * C_;
    float* out = (float*)d_out;

    // 1. transpose+split Wq/Wk/Wv
    k_tr<<<dim3(32, 32, 3), 256, 0, stream>>>(Wq, Wk, Wv, WH0, WL0, WH1, WL1, WH2, WL2);
    // 2. m1 = tanh(xxx @ maa_w1) (xxx computed on the fly)
    k_small1<<<dim3(128, 1, 1), 256, 0, stream>>>(0, hidden, maa_x, maa_w1,
        S0, gate_w1, S1, decay_w1, aaa_w1, ma_w1, S2, kkk_w1, mk_w1, m1, g1, wam, km);
    // 3. xrg/xwa/xk/xv
    k_xmix<<<dim3(8, 64), 256, 0, stream>>>(hidden, m1, maa_w2,
        maa_rg, maa_wa, maa_k, maa_v, S0, S1, S2, S3);
    // 4. stage-1 small projections (g1, wam, km)
    k_small1<<<dim3(128, 1, 3), 256, 0, stream>>>(1, hidden, maa_x, maa_w1,
        S0, gate_w1, S1, decay_w1, aaa_w1, ma_w1, S2, kkk_w1, mk_w1, m1, g1, wam, km);
    // 5. r, k0, v (split-bf16 MFMA)
    k_gemm<<<dim3(16, 8, 3), 256, 0, stream>>>(
        S0, WH0, WL0, S4,  S2, WH1, WL1, S6,  S3, WH2, WL2, S7);
    // 5.5 transpose+split Wo into slot 0 (reuse)
    k_tr<<<dim3(32, 32, 1), 256, 0, stream>>>(Wo, Wo, Wo, WH0, WL0, WH1, WL1, WH2, WL2);
    // 6. fused stage-2: w, kk_un, k_final, a_sig
    k_fuse<<<dim3(8, 64), 256, 0, stream>>>(wam, km, S6, decay_w2, aaa_w2, ma_w2,
        kkk_w2, mk_w2, tdecay, aaaaa, misc_a, misc_k, S5, S3, S2);
    // 7. kk normalize + b = kk*a
    k_kknorm<<<dim3(8, 1024), 256, 0, stream>>>(S3, S2);
    // 8. g = g1 @ gate_w2
    k_gate2<<<dim3(8, 64), 256, 0, stream>>>(g1, gate_w2, S1);
    // 9. WKV7 scan -> y (S0)
    k_wkv<<<dim3(128), 256, 0, stream>>>(S4, S5, S6, S7, S3, S2, S0);
    // 10. groupnorm + bonus + gate (in place S0)
    k_gn<<<dim3(8, 1024), 256, 0, stream>>>(S0, S4, S6, S7, S1, faaaa, lnw, lnb);
    // 11. out = (y*g) @ Wo
    k_gemm<<<dim3(16, 8, 1), 256, 0, stream>>>(
        S0, WH0, WL0, out,  S0, WH0, WL0, out,  S0, WH0, WL0, out);
}

// Round 3
// 886.174 us; speedup vs baseline: 1.5197x; 1.5197x over previous
//
#include <hip/hip_runtime.h>

// RWKV7 attention block, MI355X/gfx950.
// Shapes: B=1, T=1024, C=2048, H=32, N=64. All inputs/outputs f32.
// Big GEMMs in f16 MFMA (16x16x32, single term — f16's 11-bit mantissa gives
// ~8x less error than bf16; measured bf16 absmax 6.1e-3 -> f16 ~7.6e-4 vs
// threshold 3.89e-3). WKV scan uses DPP (VALU-pipe) reductions instead of
// shfl_xor (LDS-pipe) — the 8 serial shuffles were ~700 cyc/step.

#define T_ 1024
#define C_ 2048
#define H_ 32
#define N_ 64

using half8  = __attribute__((ext_vector_type(8))) _Float16;  // 8 f16 (4 VGPRs)
using half4  = __attribute__((ext_vector_type(4))) _Float16;  // 8 B
using floatx4 = __attribute__((ext_vector_type(4))) float;    // 4 f32 acc

// DPP xor-style add within 16-lane rows: quad_perm(0xB1)=xor1,
// quad_perm(0x4E)=xor2, row_half_mirror(0x141)=xor4*, row_mirror(0x140)=xor8*
// (*valid because value is uniform within the smaller group by that stage).
#define DPP_ADD(v, ctrl) \
    ((v) + __int_as_float(__builtin_amdgcn_update_dpp( \
        0, __float_as_int(v), (ctrl), 0xf, 0xf, true)))
#define REDUCE16(v) do { \
    v = DPP_ADD(v, 0xB1); v = DPP_ADD(v, 0x4E); \
    v = DPP_ADD(v, 0x141); v = DPP_ADD(v, 0x140); } while (0)

// ---------------------------------------------------------------------------
// Transpose + convert: W[k][n] f32 -> WT[n][k] f16 (z selects which weight)
// ---------------------------------------------------------------------------
__global__ __launch_bounds__(256) void k_tr(
    const float* __restrict__ W0, const float* __restrict__ W1,
    const float* __restrict__ W2, const float* __restrict__ W3,
    _Float16* __restrict__ D0, _Float16* __restrict__ D1,
    _Float16* __restrict__ D2, _Float16* __restrict__ D3)
{
    const int z = blockIdx.z;
    const float* S = (z == 0) ? W0 : (z == 1) ? W1 : (z == 2) ? W2 : W3;
    _Float16* D = (z == 0) ? D0 : (z == 1) ? D1 : (z == 2) ? D2 : D3;
    const int nb = blockIdx.x * 64, kb = blockIdx.y * 64;
    __shared__ __align__(16) float tile[64][65];
    const int tr = threadIdx.x >> 4, tc4 = (threadIdx.x & 15) * 4;
#pragma unroll
    for (int p = 0; p < 4; ++p) {
        int row = p * 16 + tr;
        float4 v = *(const float4*)&S[(size_t)(kb + row) * C_ + nb + tc4];
        tile[row][tc4 + 0] = v.x; tile[row][tc4 + 1] = v.y;
        tile[row][tc4 + 2] = v.z; tile[row][tc4 + 3] = v.w;
    }
    __syncthreads();
#pragma unroll
    for (int p = 0; p < 4; ++p) {
        int n = p * 16 + tr;
        half4 u;
        u[0] = (_Float16)tile[tc4 + 0][n];
        u[1] = (_Float16)tile[tc4 + 1][n];
        u[2] = (_Float16)tile[tc4 + 2][n];
        u[3] = (_Float16)tile[tc4 + 3][n];
        *(half4*)&D[(size_t)(nb + n) * C_ + kb + tc4] = u;
    }
}

// ---------------------------------------------------------------------------
// Stage-1 small projections: Y = [tanh](X @ W1). t-tile 8, 256 thr.
// mode 0: X=xxx(on-the-fly shift-mix of hidden), W=maa_w1[2048,128] -> m1, tanh
// mode 1: X=xrg, gate_w1[2048,128] -> g1, tanh
// mode 2: X=xwa, cols 0-63 decay_w1(tanh) | 64-79 aaa_w1 | 80-95 ma_w1 -> wam[T,96]
// mode 3: X=xk,  cols 0-15 kkk_w1(tanh) | 16-31 mk_w1 -> km[T,32]
// ---------------------------------------------------------------------------
__global__ __launch_bounds__(256) void k_small1(
    int mode_base,
    const float* __restrict__ hidden, const float* __restrict__ maa_x,
    const float* __restrict__ maa_w1,
    const float* __restrict__ xrg, const float* __restrict__ gate_w1,
    const float* __restrict__ xwa, const float* __restrict__ decay_w1,
    const float* __restrict__ aaa_w1, const float* __restrict__ ma_w1,
    const float* __restrict__ xk, const float* __restrict__ kkk_w1,
    const float* __restrict__ mk_w1,
    float* __restrict__ m1, float* __restrict__ g1,
    float* __restrict__ wam, float* __restrict__ km)
{
    const int mode = mode_base + blockIdx.z;
    const int t0 = blockIdx.x * 8;
    const int tid = threadIdx.x;
    const int n = tid & 127, rh = tid >> 7;

    const float* X = hidden;
    const float* Wp = maa_w1;   // safe defaults
    float* Yp = m1;
    int wstride = 128, ystride = 128;
    bool dotanh = true, act = true;

    if (mode == 0) { X = hidden; Wp = maa_w1 + n; Yp = m1 + n; }
    else if (mode == 1) { X = xrg; Wp = gate_w1 + n; Yp = g1 + n; }
    else if (mode == 2) {
        X = xwa; ystride = 96; Yp = wam + n;
        if (n < 64)      { Wp = decay_w1 + n;      wstride = 64; dotanh = true; }
        else if (n < 80) { Wp = aaa_w1 + (n - 64); wstride = 16; dotanh = false; }
        else if (n < 96) { Wp = ma_w1 + (n - 80);  wstride = 16; dotanh = false; }
        else act = false;
    } else {
        X = xk; ystride = 32; Yp = km + n;
        if (n < 16)      { Wp = kkk_w1 + n;        wstride = 16; dotanh = true; }
        else if (n < 32) { Wp = mk_w1 + (n - 16);  wstride = 16; dotanh = false; }
        else act = false;
    }

    __shared__ __align__(16) float xs[8][64];
    float acc[4] = {0.f, 0.f, 0.f, 0.f};

    for (int kc = 0; kc < C_; kc += 64) {
        {
            int r = tid >> 5, c2 = (tid & 31) * 2;
            const float* xb = X + (size_t)(t0 + r) * C_ + kc + c2;
            float2 xv = *(const float2*)xb;
            if (mode == 0) {
                float2 xp = make_float2(0.f, 0.f);
                if (t0 + r > 0) xp = *(const float2*)(xb - C_);
                float2 mx = *(const float2*)&maa_x[kc + c2];
                xv.x = xv.x + (xp.x - xv.x) * mx.x;
                xv.y = xv.y + (xp.y - xv.y) * mx.y;
            }
            *(float2*)&xs[r][c2] = xv;
        }
        __syncthreads();
        if (act) {
            for (int kk = 0; kk < 64; kk += 4) {
                float w0 = Wp[(size_t)(kc + kk + 0) * wstride];
                float w1 = Wp[(size_t)(kc + kk + 1) * wstride];
                float w2 = Wp[(size_t)(kc + kk + 2) * wstride];
                float w3 = Wp[(size_t)(kc + kk + 3) * wstride];
#pragma unroll
                for (int rr = 0; rr < 4; ++rr) {
                    float4 xr = *(float4*)&xs[rh * 4 + rr][kk];
                    acc[rr] = fmaf(xr.x, w0, fmaf(xr.y, w1, fmaf(xr.z, w2, fmaf(xr.w, w3, acc[rr]))));
                }
            }
        }
        __syncthreads();
    }
    if (act) {
#pragma unroll
        for (int rr = 0; rr < 4; ++rr) {
            float v = acc[rr];
            if (dotanh) v = tanhf(v);
            Yp[(size_t)(t0 + rh * 4 + rr) * ystride] = v;
        }
    }
}

// ---------------------------------------------------------------------------
// xmix: mix = einsum(m1[T,4,32], maa_w2[4,32,C]); xrg/xwa/xk f32 + f16 copies
// of the GEMM A-operands (xrg, xk, xv).
// ---------------------------------------------------------------------------
__global__ __launch_bounds__(256) void k_xmix(
    const float* __restrict__ X, const float* __restrict__ m1,
    const float* __restrict__ w2,
    const float* __restrict__ mrg, const float* __restrict__ mwa,
    const float* __restrict__ mk, const float* __restrict__ mv,
    float* __restrict__ xrg, float* __restrict__ xwa,
    float* __restrict__ xk,
    _Float16* __restrict__ xrgH, _Float16* __restrict__ xkH,
    _Float16* __restrict__ xvH)
{
    const int tid = threadIdx.x;
    const int c = blockIdx.x * 256 + tid;
    const int t0 = blockIdx.y * 16;
    __shared__ __align__(16) float m1s[16][128];
#pragma unroll
    for (int p = 0; p < 2; ++p) {
        int id = tid + p * 256;
        int r = id >> 5, c4 = (id & 31) * 4;
        *(float4*)&m1s[r][c4] = *(const float4*)&m1[(size_t)(t0 + r) * 128 + c4];
    }
    __syncthreads();
    float a0[16], a1[16], a2[16], a3[16];
#pragma unroll
    for (int t = 0; t < 16; ++t) { a0[t] = 0.f; a1[t] = 0.f; a2[t] = 0.f; a3[t] = 0.f; }
    for (int d = 0; d < 32; ++d) {
        float w0 = w2[(size_t)(0 * 32 + d) * C_ + c];
        float w1 = w2[(size_t)(1 * 32 + d) * C_ + c];
        float w2v = w2[(size_t)(2 * 32 + d) * C_ + c];
        float w3 = w2[(size_t)(3 * 32 + d) * C_ + c];
#pragma unroll
        for (int t = 0; t < 16; ++t) {
            a0[t] = fmaf(m1s[t][d],      w0,  a0[t]);
            a1[t] = fmaf(m1s[t][32 + d], w1,  a1[t]);
            a2[t] = fmaf(m1s[t][64 + d], w2v, a2[t]);
            a3[t] = fmaf(m1s[t][96 + d], w3,  a3[t]);
        }
    }
    float vrg = mrg[c], vwa = mwa[c], vmk = mk[c], vmv = mv[c];
    float prev = (t0 > 0) ? X[(size_t)(t0 - 1) * C_ + c] : 0.0f;
    for (int t = 0; t < 16; ++t) {
        size_t idx = (size_t)(t0 + t) * C_ + c;
        float cur = X[idx];
        float dx = prev - cur;
        float vr = cur + dx * (vrg + a0[t]);
        float vw = cur + dx * (vwa + a1[t]);
        float vk = cur + dx * (vmk + a2[t]);
        float vv = cur + dx * (vmv + a3[t]);
        xrg[idx] = vr;  xrgH[idx] = (_Float16)vr;
        xwa[idx] = vw;
        xk[idx]  = vk;  xkH[idx]  = (_Float16)vk;
        xvH[idx] = (_Float16)vv;
        prev = cur;
    }
}

// ---------------------------------------------------------------------------
// f16 MFMA GEMM: C[1024,2048] = A[1024,2048](f16) * W via WT[n][k] f16.
// BM=BN=128, BK=32, 256 thr (4 waves, 2x2), 4x4 16x16x32 tiles/wave.
// ---------------------------------------------------------------------------
__global__ __launch_bounds__(256) void k_gemm(
    const _Float16* __restrict__ A0, const _Float16* __restrict__ B0, float* __restrict__ C0,
    const _Float16* __restrict__ A1, const _Float16* __restrict__ B1, float* __restrict__ C1,
    const _Float16* __restrict__ A2, const _Float16* __restrict__ B2, float* __restrict__ C2)
{
    const int z = blockIdx.z;
    const _Float16* A = (z == 0) ? A0 : (z == 1) ? A1 : A2;
    const _Float16* Bt = (z == 0) ? B0 : (z == 1) ? B1 : B2;
    float* C = (z == 0) ? C0 : (z == 1) ? C1 : C2;
    const int mtile = blockIdx.y * 128;
    const int ntile = blockIdx.x * 128;
    const int tid = threadIdx.x;
    __shared__ __align__(16) _Float16 As[128 * 40];  // row stride 40 (pad)
    __shared__ __align__(16) _Float16 Bs[128 * 40];
    const int lane = tid & 63;
    const int wvid = tid >> 6;
    const int wm = wvid >> 1, wn = wvid & 1;
    const int r16 = lane & 15, q = lane >> 4;

    floatx4 acc[4][4];
#pragma unroll
    for (int i = 0; i < 4; ++i)
#pragma unroll
        for (int j = 0; j < 4; ++j) { floatx4 zv = {0.f, 0.f, 0.f, 0.f}; acc[i][j] = zv; }

    const int srow = tid >> 1, shalf = tid & 1;
    const _Float16* ag = A + (size_t)(mtile + srow) * C_ + shalf * 16;
    const _Float16* bg = Bt + (size_t)(ntile + srow) * C_ + shalf * 16;
    _Float16* asw = &As[srow * 40 + shalf * 16];
    _Float16* bsw = &Bs[srow * 40 + shalf * 16];

    for (int kc = 0; kc < C_; kc += 32) {
        half8 a0 = *(const half8*)(ag + kc);
        half8 a1 = *(const half8*)(ag + kc + 8);
        half8 b0 = *(const half8*)(bg + kc);
        half8 b1 = *(const half8*)(bg + kc + 8);
        *(half8*)asw = a0; *(half8*)(asw + 8) = a1;
        *(half8*)bsw = b0; *(half8*)(bsw + 8) = b1;
        __syncthreads();

        half8 af[4], bf[4];
#pragma unroll
        for (int i = 0; i < 4; ++i)
            af[i] = *(const half8*)&As[(wm * 64 + i * 16 + r16) * 40 + q * 8];
#pragma unroll
        for (int j = 0; j < 4; ++j)
            bf[j] = *(const half8*)&Bs[(wn * 64 + j * 16 + r16) * 40 + q * 8];
#pragma unroll
        for (int i = 0; i < 4; ++i)
#pragma unroll
            for (int j = 0; j < 4; ++j)
                acc[i][j] = __builtin_amdgcn_mfma_f32_16x16x32_f16(af[i], bf[j], acc[i][j], 0, 0, 0);
        __syncthreads();
    }
    // C/D layout: col = lane&15, row = (lane>>4)*4 + reg
#pragma unroll
    for (int i = 0; i < 4; ++i)
#pragma unroll
        for (int j = 0; j < 4; ++j)
#pragma unroll
            for (int e = 0; e < 4; ++e) {
                int row = mtile + wm * 64 + i * 16 + q * 4 + e;
                int col = ntile + wn * 64 + j * 16 + r16;
                C[(size_t)row * C_ + col] = acc[i][j][e];
            }
}

// ---------------------------------------------------------------------------
// Fused stage-2: w, a, ma, mk, kk_unnorm, k_final (in place over k0)
// ---------------------------------------------------------------------------
__global__ __launch_bounds__(256) void k_fuse(
    const float* __restrict__ wam, const float* __restrict__ km,
    float* __restrict__ K0,
    const float* __restrict__ decay_w2, const float* __restrict__ aaa_w2,
    const float* __restrict__ ma_w2, const float* __restrict__ kkk_w2,
    const float* __restrict__ mk_w2,
    const float* __restrict__ tdecay, const float* __restrict__ aaaaa,
    const float* __restrict__ misc_a, const float* __restrict__ misc_k,
    float* __restrict__ Wout, float* __restrict__ KKout, float* __restrict__ Aout)
{
    const int tid = threadIdx.x;
    const int c = blockIdx.x * 256 + tid;
    const int t0 = blockIdx.y * 16;
    __shared__ __align__(16) float wsS[16][96];
    __shared__ __align__(16) float ksS[16][32];
    for (int id = tid; id < 16 * 24; id += 256) {
        int r = id / 24, c4 = (id % 24) * 4;
        *(float4*)&wsS[r][c4] = *(const float4*)&wam[(size_t)(t0 + r) * 96 + c4];
    }
    for (int id = tid; id < 16 * 8; id += 256) {
        int r = id / 8, c4 = (id % 8) * 4;
        *(float4*)&ksS[r][c4] = *(const float4*)&km[(size_t)(t0 + r) * 32 + c4];
    }
    __syncthreads();
    float accW[16], accA[16], accMA[16], accKK[16], accMK[16];
#pragma unroll
    for (int r = 0; r < 16; ++r) { accW[r] = 0.f; accA[r] = 0.f; accMA[r] = 0.f; accKK[r] = 0.f; accMK[r] = 0.f; }
    for (int j = 0; j < 64; ++j) {
        float w = decay_w2[(size_t)j * C_ + c];
#pragma unroll
        for (int r = 0; r < 16; ++r) accW[r] = fmaf(wsS[r][j], w, accW[r]);
    }
    for (int j = 0; j < 16; ++j) {
        float wa = aaa_w2[(size_t)j * C_ + c];
        float wm = ma_w2[(size_t)j * C_ + c];
        float wk = kkk_w2[(size_t)j * C_ + c];
        float wq = mk_w2[(size_t)j * C_ + c];
#pragma unroll
        for (int r = 0; r < 16; ++r) {
            accA[r]  = fmaf(wsS[r][64 + j], wa, accA[r]);
            accMA[r] = fmaf(wsS[r][80 + j], wm, accMA[r]);
            accKK[r] = fmaf(ksS[r][j],      wk, accKK[r]);
            accMK[r] = fmaf(ksS[r][16 + j], wq, accMK[r]);
        }
    }
    float td = tdecay[c], aa = aaaaa[c], mia = misc_a[c], mik = misc_k[c];
    for (int r = 0; r < 16; ++r) {
        size_t idx = (size_t)(t0 + r) * C_ + c;
        float wraw = td + accW[r];
        float w = -logf(1.0f + __expf(-wraw)) - 0.5f;   // -softplus(-x) - 0.5
        float a  = 1.0f / (1.0f + __expf(-(aa  + accA[r])));
        float mav = 1.0f / (1.0f + __expf(-(mia + accMA[r])));
        float mkv = 1.0f / (1.0f + __expf(-(mik + accMK[r])));
        float k0 = K0[idx];
        Wout[idx]  = w;
        KKout[idx] = k0 + accKK[r];
        K0[idx]    = k0 * (mav + a * (1.0f - mav)) * __expf(fminf(w * mkv, 0.0f));
        Aout[idx]  = a;
    }
}

// ---------------------------------------------------------------------------
// kk L2-normalize per (t,head); b = kk_hat * a_sig written over a_sig.
// ---------------------------------------------------------------------------
__global__ __launch_bounds__(256) void k_kknorm(float* __restrict__ KK, float* __restrict__ Ab)
{
    const int t = blockIdx.y;
    const int c = blockIdx.x * 256 + threadIdx.x;
    const size_t idx = (size_t)t * C_ + c;
    float kv = KK[idx];
    float ss = kv * kv;
    REDUCE16(ss);
    ss = DPP_ADD(ss, 0x142);                 // row_bcast15: 16->32 partial
    ss += __shfl_xor(ss, 32, 64);            // not needed within head (N=64 spans 64 lanes? no)
    // NOTE: head spans 64 channels = 64 consecutive lanes when blockDim=256:
    // lanes 0-63 of each wave cover one head exactly? c = bx*256+tid, head = c/64:
    // each 64-lane run IS one head. Full 64-lane reduction required.
    // REDUCE16 + bcast15 handles 32; the shfl handles 64. (bcast15: lane
    // 16-31 add lane15's 16-sum; gives 32-sum in lanes 16-31; mirror back:)
    // -- Simpler correct path below overrides: recompute with shfl pairs. --
    float kv2 = KK[idx];
    float s2 = kv2 * kv2;
    s2 += __shfl_xor(s2, 1, 64);  s2 += __shfl_xor(s2, 2, 64);
    s2 += __shfl_xor(s2, 4, 64);  s2 += __shfl_xor(s2, 8, 64);
    s2 += __shfl_xor(s2, 16, 64); s2 += __shfl_xor(s2, 32, 64);
    float scale = 1.0f / fmaxf(sqrtf(s2), 1e-12f);
    float kn = kv * scale;
    KK[idx] = kn;
    Ab[idx] = kn * Ab[idx];
}

// ---------------------------------------------------------------------------
// Gate stage-2: G = g1[T,128] @ gate_w2[128,2048]
// ---------------------------------------------------------------------------
__global__ __launch_bounds__(256) void k_gate2(
    const float* __restrict__ g1, const float* __restrict__ w2, float* __restrict__ G)
{
    const int tid = threadIdx.x;
    const int c = blockIdx.x * 256 + tid;
    const int t0 = blockIdx.y * 16;
    __shared__ __align__(16) float gs[16][128];
#pragma unroll
    for (int p = 0; p < 2; ++p) {
        int id = tid + p * 256;
        int r = id >> 5, c4 = (id & 31) * 4;
        *(float4*)&gs[r][c4] = *(const float4*)&g1[(size_t)(t0 + r) * 128 + c4];
    }
    __syncthreads();
    float acc[16];
#pragma unroll
    for (int r = 0; r < 16; ++r) acc[r] = 0.f;
    for (int j = 0; j < 128; ++j) {
        float w = w2[(size_t)j * C_ + c];
#pragma unroll
        for (int r = 0; r < 16; ++r) acc[r] = fmaf(gs[r][j], w, acc[r]);
    }
    for (int r = 0; r < 16; ++r) G[(size_t)(t0 + r) * C_ + c] = acc[r];
}

// ---------------------------------------------------------------------------
// WKV7 scan. 4 blocks/head; 256 thr; wave covers 4 rows x 16 j-groups.
// DPP reductions (VALU pipe) replace shfl_xor (LDS pipe) on the critical path.
// ---------------------------------------------------------------------------
__global__ __launch_bounds__(256) void k_wkv(
    const float* __restrict__ R, const float* __restrict__ Wd,
    const float* __restrict__ K, const float* __restrict__ V,
    const float* __restrict__ KK, const float* __restrict__ Bb,
    float* __restrict__ Y)
{
    const int tid = threadIdx.x;
    const int h = blockIdx.x >> 2;
    const int rg = blockIdx.x & 3;
    const int c0 = h * 64;
    const int wv = tid >> 6, lane = tid & 63;
    const int irow = rg * 16 + wv * 4 + (lane >> 4);
    const int jg = lane & 15;
    __shared__ __align__(16) float rS[16][64], dS[16][64], kS[16][64],
                                   vS[16][64], aS[16][64], bS[16][64], oS[16][64];
    float4 s = make_float4(0.f, 0.f, 0.f, 0.f);
    const int tloc = tid >> 4, j4 = (tid & 15) * 4;

    for (int tc = 0; tc < T_; tc += 16) {
        size_t gi = (size_t)(tc + tloc) * C_ + c0 + j4;
        *(float4*)&rS[tloc][j4] = *(const float4*)&R[gi];
        float4 w4 = *(const float4*)&Wd[gi];
        float4 d4;
        d4.x = __expf(w4.x); d4.y = __expf(w4.y); d4.z = __expf(w4.z); d4.w = __expf(w4.w);
        *(float4*)&dS[tloc][j4] = d4;
        *(float4*)&kS[tloc][j4] = *(const float4*)&K[gi];
        *(float4*)&vS[tloc][j4] = *(const float4*)&V[gi];
        float4 kk4 = *(const float4*)&KK[gi];
        float4 a4 = make_float4(-kk4.x, -kk4.y, -kk4.z, -kk4.w);
        *(float4*)&aS[tloc][j4] = a4;
        *(float4*)&bS[tloc][j4] = *(const float4*)&Bb[gi];
        __syncthreads();

#pragma unroll
        for (int tt = 0; tt < 16; ++tt) {
            float4 a = *(float4*)&aS[tt][jg * 4];
            float sa = s.x * a.x + s.y * a.y + s.z * a.z + s.w * a.w;
            REDUCE16(sa);
            float vi = vS[tt][irow];
            float4 d = *(float4*)&dS[tt][jg * 4];
            float4 b = *(float4*)&bS[tt][jg * 4];
            float4 k = *(float4*)&kS[tt][jg * 4];
            s.x = fmaf(s.x, d.x, fmaf(sa, b.x, vi * k.x));
            s.y = fmaf(s.y, d.y, fmaf(sa, b.y, vi * k.y));
            s.z = fmaf(s.z, d.z, fmaf(sa, b.z, vi * k.z));
            s.w = fmaf(s.w, d.w, fmaf(sa, b.w, vi * k.w));
            float4 r = *(float4*)&rS[tt][jg * 4];
            float o = s.x * r.x + s.y * r.y + s.z * r.z + s.w * r.w;
            REDUCE16(o);
            if (jg == 0) oS[tt][irow] = o;
        }
        __syncthreads();
        Y[(size_t)(tc + tloc) * C_ + c0 + rg * 16 + (tid & 15)] = oS[tloc][rg * 16 + (tid & 15)];
    }
}

// ---------------------------------------------------------------------------
// GroupNorm(y) * ln_w + ln_b, + bonus, * gate -> f16 (A-operand of Wo GEMM)
// ---------------------------------------------------------------------------
__global__ __launch_bounds__(256) void k_gn(
    const float* __restrict__ Y, const float* __restrict__ R, const float* __restrict__ K,
    const float* __restrict__ V, const float* __restrict__ G,
    const float* __restrict__ faaaa, const float* __restrict__ lnw,
    const float* __restrict__ lnb, _Float16* __restrict__ YG)
{
    const int t = blockIdx.y;
    const int c = blockIdx.x * 256 + threadIdx.x;
    const size_t idx = (size_t)t * C_ + c;
    float y = Y[idx];
    float s1 = y, s2 = y * y;
#pragma unroll
    for (int off = 1; off < 64; off <<= 1) {
        s1 += __shfl_xor(s1, off, 64);
        s2 += __shfl_xor(s2, off, 64);
    }
    float mu = s1 * (1.0f / 64.0f);
    float var = s2 * (1.0f / 64.0f) - mu * mu;
    float gn = (y - mu) * rsqrtf(var + 0.00064f) * lnw[c] + lnb[c];
    float p = R[idx] * K[idx] * faaaa[c];
#pragma unroll
    for (int off = 1; off < 64; off <<= 1) p += __shfl_xor(p, off, 64);
    float y2 = gn + p * V[idx];
    YG[idx] = (_Float16)(y2 * G[idx]);
}

// ---------------------------------------------------------------------------
extern "C" void kernel_launch(void* const* d_in, const int* in_sizes, int n_in,
                              void* d_out, int out_size, void* d_ws, size_t ws_size,
                              hipStream_t stream)
{
    (void)in_sizes; (void)n_in; (void)out_size; (void)ws_size;
    const float* hidden   = (const float*)d_in[0];
    const float* Wq       = (const float*)d_in[1];
    const float* Wk       = (const float*)d_in[2];
    const float* Wv       = (const float*)d_in[3];
    const float* Wo       = (const float*)d_in[4];
    const float* maa_x    = (const float*)d_in[5];
    const float* maa_rg   = (const float*)d_in[6];
    const float* maa_wa   = (const float*)d_in[7];
    const float* maa_k    = (const float*)d_in[8];
    const float* maa_v    = (const float*)d_in[9];
    const float* maa_w1   = (const float*)d_in[10];
    const float* maa_w2   = (const float*)d_in[11];
    const float* tdecay   = (const float*)d_in[12];
    const float* decay_w1 = (const float*)d_in[13];
    const float* decay_w2 = (const float*)d_in[14];
    const float* aaaaa    = (const float*)d_in[15];
    const float* aaa_w1   = (const float*)d_in[16];
    const float* aaa_w2   = (const float*)d_in[17];
    const float* kkk_w1   = (const float*)d_in[18];
    const float* kkk_w2   = (const float*)d_in[19];
    const float* gate_w1  = (const float*)d_in[20];
    const float* gate_w2  = (const float*)d_in[21];
    const float* misc_a   = (const float*)d_in[22];
    const float* ma_w1    = (const float*)d_in[23];
    const float* ma_w2    = (const float*)d_in[24];
    const float* misc_k   = (const float*)d_in[25];
    const float* mk_w1    = (const float*)d_in[26];
    const float* mk_w2    = (const float*)d_in[27];
    const float* faaaa    = (const float*)d_in[28];
    const float* lnw      = (const float*)d_in[29];
    const float* lnb      = (const float*)d_in[30];

    float* ws = (float*)d_ws;
    const size_t TC = (size_t)T_ * C_;
    // f32 buffers:
    //   S0: xrg -> y        S1: xwa -> g        S2: xk -> a_sig -> b
    //   S3: kk              S4: r               S5: w
    //   S6: k0 -> k_final   S7: v
    float* S0 = ws + 0 * TC;
    float* S1 = ws + 1 * TC;
    float* S2 = ws + 2 * TC;
    float* S3 = ws + 3 * TC;
    float* S4 = ws + 4 * TC;
    float* S5 = ws + 5 * TC;
    float* S6 = ws + 6 * TC;
    float* S7 = ws + 7 * TC;
    float* m1  = ws + 8 * TC;              // [T,128]
    float* g1  = m1 + (size_t)T_ * 128;    // [T,128]
    float* wam = g1 + (size_t)T_ * 128;    // [T,96]
    float* km  = wam + (size_t)T_ * 96;    // [T,32]
    // f16 region: 4 x C*C weights + 4 x T*C activations
    _Float16* WTq = (_Float16*)(km + (size_t)T_ * 32);
    _Float16* WTk = WTq + (size_t)C_ * C_;
    _Float16* WTv = WTk + (size_t)C_ * C_;
    _Float16* WTo = WTv + (size_t)C_ * C_;
    _Float16* xrgH = WTo + (size_t)C_ * C_;
    _Float16* xkH  = xrgH + TC;
    _Float16* xvH  = xkH + TC;
    _Float16* ygH  = xvH + TC;
    float* out = (float*)d_out;

    // 1. transpose+convert all four big weights
    k_tr<<<dim3(32, 32, 4), 256, 0, stream>>>(Wq, Wk, Wv, Wo, WTq, WTk, WTv, WTo);
    // 2. m1 = tanh(xxx @ maa_w1) (xxx computed on the fly)
    k_small1<<<dim3(128, 1, 1), 256, 0, stream>>>(0, hidden, maa_x, maa_w1,
        S0, gate_w1, S1, decay_w1, aaa_w1, ma_w1, S2, kkk_w1, mk_w1, m1, g1, wam, km);
    // 3. xrg/xwa/xk f32 + xrg/xk/xv f16
    k_xmix<<<dim3(8, 64), 256, 0, stream>>>(hidden, m1, maa_w2,
        maa_rg, maa_wa, maa_k, maa_v, S0, S1, S2, xrgH, xkH, xvH);
    // 4. stage-1 small projections (g1, wam, km)
    k_small1<<<dim3(128, 1, 3), 256, 0, stream>>>(1, hidden, maa_x, maa_w1,
        S0, gate_w1, S1, decay_w1, aaa_w1, ma_w1, S2, kkk_w1, mk_w1, m1, g1, wam, km);
    // 5. r, k0, v (f16 MFMA)
    k_gemm<<<dim3(16, 8, 3), 256, 0, stream>>>(
        xrgH, WTq, S4,  xkH, WTk, S6,  xvH, WTv, S7);
    // 6. fused stage-2: w, kk_un, k_final, a_sig
    k_fuse<<<dim3(8, 64), 256, 0, stream>>>(wam, km, S6, decay_w2, aaa_w2, ma_w2,
        kkk_w2, mk_w2, tdecay, aaaaa, misc_a, misc_k, S5, S3, S2);
    // 7. kk normalize + b = kk*a
    k_kknorm<<<dim3(8, 1024), 256, 0, stream>>>(S3, S2);
    // 8. g = g1 @ gate_w2
    k_gate2<<<dim3(8, 64), 256, 0, stream>>>(g1, gate_w2, S1);
    // 9. WKV7 scan -> y (S0)
    k_wkv<<<dim3(128), 256, 0, stream>>>(S4, S5, S6, S7, S3, S2, S0);
    // 10. groupnorm + bonus + gate -> f16
    k_gn<<<dim3(8, 1024), 256, 0, stream>>>(S0, S4, S6, S7, S1, faaaa, lnw, lnb, ygH);
    // 11. out = (y*g) @ Wo
    k_gemm<<<dim3(16, 8, 1), 256, 0, stream>>>(
        ygH, WTo, out,  ygH, WTo, out,  ygH, WTo, out);
}

// Round 5
// 604.451 us; speedup vs baseline: 2.2280x; 1.4661x over previous
//
#include <hip/hip_runtime.h>

// RWKV7 attention block, MI355X/gfx950.
// B=1, T=1024, C=2048, H=32, N=64. All inputs/outputs f32.
// Big GEMMs: f16 MFMA 16x16x32 (f32-accum). LoRA stage-1: MFMA split-K with
// DETERMINISTIC per-split partials (plain stores; consumers sum in fixed
// order — f32 atomicAdd tripped the graph-replay bitwise tripwire in r4).
// WKV scan: DPP 16-lane reductions (VALU pipe).

#define T_ 1024
#define C_ 2048
#define H_ 32
#define N_ 64

using half8  = __attribute__((ext_vector_type(8))) _Float16;  // 8 f16 (4 VGPRs)
using half4  = __attribute__((ext_vector_type(4))) _Float16;  // 8 B
using floatx4 = __attribute__((ext_vector_type(4))) float;    // 4 f32 acc

// DPP xor-add within 16-lane rows: quad_perm(0xB1)=xor1, quad_perm(0x4E)=xor2,
// row_half_mirror(0x141)=xor4, row_mirror(0x140)=xor8.
#define DPP_ADD(v, ctrl) \
    ((v) + __int_as_float(__builtin_amdgcn_update_dpp( \
        0, __float_as_int(v), (ctrl), 0xf, 0xf, true)))
#define REDUCE16(v) do { \
    v = DPP_ADD(v, 0xB1); v = DPP_ADD(v, 0x4E); \
    v = DPP_ADD(v, 0x141); v = DPP_ADD(v, 0x140); } while (0)

// ---------------------------------------------------------------------------
// Transpose + convert big weights: W[k][n] f32 -> WT[n][k] f16
// ---------------------------------------------------------------------------
__global__ __launch_bounds__(256) void k_tr(
    const float* __restrict__ W0, const float* __restrict__ W1,
    const float* __restrict__ W2, const float* __restrict__ W3,
    _Float16* __restrict__ D0, _Float16* __restrict__ D1,
    _Float16* __restrict__ D2, _Float16* __restrict__ D3)
{
    const int z = blockIdx.z;
    const float* S = (z == 0) ? W0 : (z == 1) ? W1 : (z == 2) ? W2 : W3;
    _Float16* D = (z == 0) ? D0 : (z == 1) ? D1 : (z == 2) ? D2 : D3;
    const int nb = blockIdx.x * 64, kb = blockIdx.y * 64;
    __shared__ __align__(16) float tile[64][65];
    const int tr = threadIdx.x >> 4, tc4 = (threadIdx.x & 15) * 4;
#pragma unroll
    for (int p = 0; p < 4; ++p) {
        int row = p * 16 + tr;
        float4 v = *(const float4*)&S[(size_t)(kb + row) * C_ + nb + tc4];
        tile[row][tc4 + 0] = v.x; tile[row][tc4 + 1] = v.y;
        tile[row][tc4 + 2] = v.z; tile[row][tc4 + 3] = v.w;
    }
    __syncthreads();
#pragma unroll
    for (int p = 0; p < 4; ++p) {
        int n = p * 16 + tr;
        half4 u;
        u[0] = (_Float16)tile[tc4 + 0][n];
        u[1] = (_Float16)tile[tc4 + 1][n];
        u[2] = (_Float16)tile[tc4 + 2][n];
        u[3] = (_Float16)tile[tc4 + 3][n];
        *(half4*)&D[(size_t)(nb + n) * C_ + kb + tc4] = u;
    }
}

// ---------------------------------------------------------------------------
// Pack+transpose LoRA weights to f16 WT[n][k].
// z=0: WT_m [128][2048] <- maa_w1[2048,128]
// z=1: WT_l [256][2048] <- gate(128) | decay(64) | aaa(16) | ma(16) | kkk(16) | mk(16)
// ---------------------------------------------------------------------------
__global__ __launch_bounds__(256) void k_trW(
    const float* __restrict__ maa_w1, const float* __restrict__ gate_w1,
    const float* __restrict__ decay_w1, const float* __restrict__ aaa_w1,
    const float* __restrict__ ma_w1, const float* __restrict__ kkk_w1,
    const float* __restrict__ mk_w1,
    _Float16* __restrict__ WTm, _Float16* __restrict__ WTl)
{
    const int z = blockIdx.z;
    const int k = blockIdx.x * 256 + threadIdx.x;   // 0..2047
    const int n = blockIdx.y;
    if (z == 0 && n >= 128) return;
    const float* src; int stride, col;
    _Float16* dst;
    if (z == 0) { src = maa_w1; stride = 128; col = n; dst = WTm; }
    else {
        dst = WTl;
        if (n < 128)      { src = gate_w1;  stride = 128; col = n; }
        else if (n < 192) { src = decay_w1; stride = 64;  col = n - 128; }
        else if (n < 208) { src = aaa_w1;   stride = 16;  col = n - 192; }
        else if (n < 224) { src = ma_w1;    stride = 16;  col = n - 208; }
        else if (n < 240) { src = kkk_w1;   stride = 16;  col = n - 224; }
        else              { src = mk_w1;    stride = 16;  col = n - 240; }
    }
    dst[(size_t)n * C_ + k] = (_Float16)src[(size_t)k * stride + col];
}

// ---------------------------------------------------------------------------
// xxxH = f16( x + (x_prev - x) * maa_x )
// ---------------------------------------------------------------------------
__global__ __launch_bounds__(256) void k_prep(
    const float* __restrict__ X, const float* __restrict__ maa_x,
    _Float16* __restrict__ xxxH)
{
    const size_t idx = (size_t)blockIdx.x * 256 + threadIdx.x;
    const int c = (int)(idx & (C_ - 1));
    float cur = X[idx];
    float prev = (idx >= C_) ? X[idx - C_] : 0.0f;
    xxxH[idx] = (_Float16)(cur + (prev - cur) * maa_x[c]);
}

// ---------------------------------------------------------------------------
// LoRA MFMA GEMM, split-K -> per-split partials (deterministic; no atomics).
// BM=64, BN=32, BK=32, ksplit=4.
// which=0: m1p[ks][1024][128] = xxxH @ WTm^T (4 n-tiles)
// which=1: l2p[ks][1024][256], A per n-tile: 0-3 xrg | 4-6 xwa | 7 xk
// Outputs are RAW partial sums; consumers reduce + activate.
// ---------------------------------------------------------------------------
__global__ __launch_bounds__(256) void k_lora(
    int which,
    const _Float16* __restrict__ Axxx, const _Float16* __restrict__ Axrg,
    const _Float16* __restrict__ Axwa, const _Float16* __restrict__ Axk,
    const _Float16* __restrict__ WTm, const _Float16* __restrict__ WTl,
    float* __restrict__ m1p, float* __restrict__ l2p)
{
    const int mt = blockIdx.x;      // 16 tiles of 64 rows
    const int nt = blockIdx.y;      // tiles of 32 cols
    const int ks = blockIdx.z;      // 4 K-chunks of 512
    const _Float16* A; const _Float16* BT; float* O; int ostride;
    if (which == 0) { A = Axxx; BT = WTm; O = m1p; ostride = 128; }
    else {
        BT = WTl; O = l2p; ostride = 256;
        A = (nt < 4) ? Axrg : (nt < 7) ? Axwa : Axk;
    }
    O += (size_t)ks * T_ * ostride;
    const int m0 = mt * 64, n0 = nt * 32, k0 = ks * 512;
    const int tid = threadIdx.x;
    __shared__ __align__(16) _Float16 As[64 * 40];
    __shared__ __align__(16) _Float16 Bs[32 * 40];
    const int lane = tid & 63, wv = tid >> 6;
    const int r16 = lane & 15, q = lane >> 4;

    floatx4 acc[2];
    { floatx4 zv = {0.f, 0.f, 0.f, 0.f}; acc[0] = zv; acc[1] = zv; }

    const int arow = tid >> 2, ac8 = (tid & 3) * 8;
    const _Float16* ag = A + (size_t)(m0 + arow) * C_ + k0 + ac8;
    const _Float16* bg = BT + (size_t)(n0 + (tid >> 2)) * C_ + k0 + ac8;

    for (int kc = 0; kc < 512; kc += 32) {
        half8 av = *(const half8*)(ag + kc);
        half8 bv;
        if (tid < 128) bv = *(const half8*)(bg + kc);
        *(half8*)&As[arow * 40 + ac8] = av;
        if (tid < 128) *(half8*)&Bs[(tid >> 2) * 40 + ac8] = bv;
        __syncthreads();
        half8 af = *(const half8*)&As[(wv * 16 + r16) * 40 + q * 8];
        half8 b0 = *(const half8*)&Bs[(r16) * 40 + q * 8];
        half8 b1 = *(const half8*)&Bs[(16 + r16) * 40 + q * 8];
        acc[0] = __builtin_amdgcn_mfma_f32_16x16x32_f16(af, b0, acc[0], 0, 0, 0);
        acc[1] = __builtin_amdgcn_mfma_f32_16x16x32_f16(af, b1, acc[1], 0, 0, 0);
        __syncthreads();
    }
#pragma unroll
    for (int j = 0; j < 2; ++j)
#pragma unroll
        for (int e = 0; e < 4; ++e) {
            int row = m0 + wv * 16 + q * 4 + e;
            int col = n0 + j * 16 + r16;
            O[(size_t)row * ostride + col] = acc[j][e];
        }
}

// ---------------------------------------------------------------------------
// xmix: m1 = sum_ks(m1p), tanh; mix = einsum(m1[T,4,32], maa_w2[4,32,C]);
// emit f16 GEMM operands xrgH/xwaH/xkH/xvH.
// ---------------------------------------------------------------------------
__global__ __launch_bounds__(256) void k_xmix(
    const float* __restrict__ X, const float* __restrict__ m1p,
    const float* __restrict__ w2,
    const float* __restrict__ mrg, const float* __restrict__ mwa,
    const float* __restrict__ mk, const float* __restrict__ mv,
    _Float16* __restrict__ xrgH, _Float16* __restrict__ xwaH,
    _Float16* __restrict__ xkH, _Float16* __restrict__ xvH)
{
    const int tid = threadIdx.x;
    const int c = blockIdx.x * 256 + tid;
    const int t0 = blockIdx.y * 16;
    const size_t P = (size_t)T_ * 128;
    __shared__ __align__(16) float m1s[16][128];
#pragma unroll
    for (int p = 0; p < 2; ++p) {
        int id = tid + p * 256;
        int r = id >> 5, c4 = (id & 31) * 4;
        size_t off = (size_t)(t0 + r) * 128 + c4;
        float4 v0 = *(const float4*)&m1p[off];
        float4 v1 = *(const float4*)&m1p[P + off];
        float4 v2 = *(const float4*)&m1p[2 * P + off];
        float4 v3 = *(const float4*)&m1p[3 * P + off];
        float4 v;
        v.x = tanhf(((v0.x + v1.x) + v2.x) + v3.x);
        v.y = tanhf(((v0.y + v1.y) + v2.y) + v3.y);
        v.z = tanhf(((v0.z + v1.z) + v2.z) + v3.z);
        v.w = tanhf(((v0.w + v1.w) + v2.w) + v3.w);
        *(float4*)&m1s[r][c4] = v;
    }
    __syncthreads();
    float a0[16], a1[16], a2[16], a3[16];
#pragma unroll
    for (int t = 0; t < 16; ++t) { a0[t] = 0.f; a1[t] = 0.f; a2[t] = 0.f; a3[t] = 0.f; }
    for (int d = 0; d < 32; ++d) {
        float w0 = w2[(size_t)(0 * 32 + d) * C_ + c];
        float w1 = w2[(size_t)(1 * 32 + d) * C_ + c];
        float w2v = w2[(size_t)(2 * 32 + d) * C_ + c];
        float w3 = w2[(size_t)(3 * 32 + d) * C_ + c];
#pragma unroll
        for (int t = 0; t < 16; ++t) {
            a0[t] = fmaf(m1s[t][d],      w0,  a0[t]);
            a1[t] = fmaf(m1s[t][32 + d], w1,  a1[t]);
            a2[t] = fmaf(m1s[t][64 + d], w2v, a2[t]);
            a3[t] = fmaf(m1s[t][96 + d], w3,  a3[t]);
        }
    }
    float vrg = mrg[c], vwa = mwa[c], vmk = mk[c], vmv = mv[c];
    float prev = (t0 > 0) ? X[(size_t)(t0 - 1) * C_ + c] : 0.0f;
    for (int t = 0; t < 16; ++t) {
        size_t idx = (size_t)(t0 + t) * C_ + c;
        float cur = X[idx];
        float dx = prev - cur;
        xrgH[idx] = (_Float16)(cur + dx * (vrg + a0[t]));
        xwaH[idx] = (_Float16)(cur + dx * (vwa + a1[t]));
        xkH[idx]  = (_Float16)(cur + dx * (vmk + a2[t]));
        xvH[idx]  = (_Float16)(cur + dx * (vmv + a3[t]));
        prev = cur;
    }
}

// ---------------------------------------------------------------------------
// f16 MFMA GEMM: C[1024,2048] = A(f16) @ W via WT[n][k] f16.
// BM=BN=128, BK=32, 256 thr (4 waves 2x2), 4x4 16x16x32 tiles/wave.
// ---------------------------------------------------------------------------
__global__ __launch_bounds__(256) void k_gemm(
    const _Float16* __restrict__ A0, const _Float16* __restrict__ B0, float* __restrict__ C0,
    const _Float16* __restrict__ A1, const _Float16* __restrict__ B1, float* __restrict__ C1,
    const _Float16* __restrict__ A2, const _Float16* __restrict__ B2, float* __restrict__ C2)
{
    const int z = blockIdx.z;
    const _Float16* A = (z == 0) ? A0 : (z == 1) ? A1 : A2;
    const _Float16* Bt = (z == 0) ? B0 : (z == 1) ? B1 : B2;
    float* C = (z == 0) ? C0 : (z == 1) ? C1 : C2;
    const int mtile = blockIdx.y * 128;
    const int ntile = blockIdx.x * 128;
    const int tid = threadIdx.x;
    __shared__ __align__(16) _Float16 As[128 * 40];
    __shared__ __align__(16) _Float16 Bs[128 * 40];
    const int lane = tid & 63;
    const int wvid = tid >> 6;
    const int wm = wvid >> 1, wn = wvid & 1;
    const int r16 = lane & 15, q = lane >> 4;

    floatx4 acc[4][4];
#pragma unroll
    for (int i = 0; i < 4; ++i)
#pragma unroll
        for (int j = 0; j < 4; ++j) { floatx4 zv = {0.f, 0.f, 0.f, 0.f}; acc[i][j] = zv; }

    const int srow = tid >> 1, shalf = tid & 1;
    const _Float16* ag = A + (size_t)(mtile + srow) * C_ + shalf * 16;
    const _Float16* bg = Bt + (size_t)(ntile + srow) * C_ + shalf * 16;
    _Float16* asw = &As[srow * 40 + shalf * 16];
    _Float16* bsw = &Bs[srow * 40 + shalf * 16];

    for (int kc = 0; kc < C_; kc += 32) {
        half8 a0 = *(const half8*)(ag + kc);
        half8 a1 = *(const half8*)(ag + kc + 8);
        half8 b0 = *(const half8*)(bg + kc);
        half8 b1 = *(const half8*)(bg + kc + 8);
        *(half8*)asw = a0; *(half8*)(asw + 8) = a1;
        *(half8*)bsw = b0; *(half8*)(bsw + 8) = b1;
        __syncthreads();

        half8 af[4], bf[4];
#pragma unroll
        for (int i = 0; i < 4; ++i)
            af[i] = *(const half8*)&As[(wm * 64 + i * 16 + r16) * 40 + q * 8];
#pragma unroll
        for (int j = 0; j < 4; ++j)
            bf[j] = *(const half8*)&Bs[(wn * 64 + j * 16 + r16) * 40 + q * 8];
#pragma unroll
        for (int i = 0; i < 4; ++i)
#pragma unroll
            for (int j = 0; j < 4; ++j)
                acc[i][j] = __builtin_amdgcn_mfma_f32_16x16x32_f16(af[i], bf[j], acc[i][j], 0, 0, 0);
        __syncthreads();
    }
    // C/D layout: col = lane&15, row = (lane>>4)*4 + reg
#pragma unroll
    for (int i = 0; i < 4; ++i)
#pragma unroll
        for (int j = 0; j < 4; ++j)
#pragma unroll
            for (int e = 0; e < 4; ++e) {
                int row = mtile + wm * 64 + i * 16 + q * 4 + e;
                int col = ntile + wn * 64 + j * 16 + r16;
                C[(size_t)row * C_ + col] = acc[i][j][e];
            }
}

// ---------------------------------------------------------------------------
// Fused stage-2: w, a, ma, mk, kk_unnorm, k_final (in place over k0).
// l2p partials [4][T][256]: cols 128-191 decay(tanh) | 192-207 aaa |
// 208-223 ma | 224-239 kkk(tanh) | 240-255 mk. Fixed-order reduce.
// ---------------------------------------------------------------------------
__global__ __launch_bounds__(256) void k_fuse(
    const float* __restrict__ l2p,
    float* __restrict__ K0,
    const float* __restrict__ decay_w2, const float* __restrict__ aaa_w2,
    const float* __restrict__ ma_w2, const float* __restrict__ kkk_w2,
    const float* __restrict__ mk_w2,
    const float* __restrict__ tdecay, const float* __restrict__ aaaaa,
    const float* __restrict__ misc_a, const float* __restrict__ misc_k,
    float* __restrict__ Wout, float* __restrict__ KKout, float* __restrict__ Aout)
{
    const int tid = threadIdx.x;
    const int c = blockIdx.x * 256 + tid;
    const int t0 = blockIdx.y * 16;
    const size_t P = (size_t)T_ * 256;
    __shared__ __align__(16) float wsS[16][96];   // decay64 | aaa16 | ma16
    __shared__ __align__(16) float ksS[16][32];   // kkk16 | mk16
    for (int id = tid; id < 16 * 24; id += 256) {
        int r = id / 24, c4 = (id % 24) * 4;
        size_t off = (size_t)(t0 + r) * 256 + 128 + c4;
        float4 v0 = *(const float4*)&l2p[off];
        float4 v1 = *(const float4*)&l2p[P + off];
        float4 v2 = *(const float4*)&l2p[2 * P + off];
        float4 v3 = *(const float4*)&l2p[3 * P + off];
        float4 v;
        v.x = ((v0.x + v1.x) + v2.x) + v3.x;
        v.y = ((v0.y + v1.y) + v2.y) + v3.y;
        v.z = ((v0.z + v1.z) + v2.z) + v3.z;
        v.w = ((v0.w + v1.w) + v2.w) + v3.w;
        if (c4 < 64) { v.x = tanhf(v.x); v.y = tanhf(v.y); v.z = tanhf(v.z); v.w = tanhf(v.w); }
        *(float4*)&wsS[r][c4] = v;
    }
    for (int id = tid; id < 16 * 8; id += 256) {
        int r = id / 8, c4 = (id % 8) * 4;
        size_t off = (size_t)(t0 + r) * 256 + 224 + c4;
        float4 v0 = *(const float4*)&l2p[off];
        float4 v1 = *(const float4*)&l2p[P + off];
        float4 v2 = *(const float4*)&l2p[2 * P + off];
        float4 v3 = *(const float4*)&l2p[3 * P + off];
        float4 v;
        v.x = ((v0.x + v1.x) + v2.x) + v3.x;
        v.y = ((v0.y + v1.y) + v2.y) + v3.y;
        v.z = ((v0.z + v1.z) + v2.z) + v3.z;
        v.w = ((v0.w + v1.w) + v2.w) + v3.w;
        if (c4 < 16) { v.x = tanhf(v.x); v.y = tanhf(v.y); v.z = tanhf(v.z); v.w = tanhf(v.w); }
        *(float4*)&ksS[r][c4] = v;
    }
    __syncthreads();
    float accW[16], accA[16], accMA[16], accKK[16], accMK[16];
#pragma unroll
    for (int r = 0; r < 16; ++r) { accW[r] = 0.f; accA[r] = 0.f; accMA[r] = 0.f; accKK[r] = 0.f; accMK[r] = 0.f; }
    for (int j = 0; j < 64; ++j) {
        float w = decay_w2[(size_t)j * C_ + c];
#pragma unroll
        for (int r = 0; r < 16; ++r) accW[r] = fmaf(wsS[r][j], w, accW[r]);
    }
    for (int j = 0; j < 16; ++j) {
        float wa = aaa_w2[(size_t)j * C_ + c];
        float wm = ma_w2[(size_t)j * C_ + c];
        float wk = kkk_w2[(size_t)j * C_ + c];
        float wq = mk_w2[(size_t)j * C_ + c];
#pragma unroll
        for (int r = 0; r < 16; ++r) {
            accA[r]  = fmaf(wsS[r][64 + j], wa, accA[r]);
            accMA[r] = fmaf(wsS[r][80 + j], wm, accMA[r]);
            accKK[r] = fmaf(ksS[r][j],      wk, accKK[r]);
            accMK[r] = fmaf(ksS[r][16 + j], wq, accMK[r]);
        }
    }
    float td = tdecay[c], aa = aaaaa[c], mia = misc_a[c], mik = misc_k[c];
    for (int r = 0; r < 16; ++r) {
        size_t idx = (size_t)(t0 + r) * C_ + c;
        float wraw = td + accW[r];
        float w = -logf(1.0f + __expf(-wraw)) - 0.5f;   // -softplus(-x) - 0.5
        float a  = 1.0f / (1.0f + __expf(-(aa  + accA[r])));
        float mav = 1.0f / (1.0f + __expf(-(mia + accMA[r])));
        float mkv = 1.0f / (1.0f + __expf(-(mik + accMK[r])));
        float k0 = K0[idx];
        Wout[idx]  = w;
        KKout[idx] = k0 + accKK[r];
        K0[idx]    = k0 * (mav + a * (1.0f - mav)) * __expf(fminf(w * mkv, 0.0f));
        Aout[idx]  = a;
    }
}

// ---------------------------------------------------------------------------
// kk L2-normalize per (t,head); b = kk_hat * a_sig written over a_sig.
// ---------------------------------------------------------------------------
__global__ __launch_bounds__(256) void k_kknorm(float* __restrict__ KK, float* __restrict__ Ab)
{
    const int t = blockIdx.y;
    const int c = blockIdx.x * 256 + threadIdx.x;
    const size_t idx = (size_t)t * C_ + c;
    float kv = KK[idx];
    float ss = kv * kv;
    ss += __shfl_xor(ss, 1, 64);  ss += __shfl_xor(ss, 2, 64);
    ss += __shfl_xor(ss, 4, 64);  ss += __shfl_xor(ss, 8, 64);
    ss += __shfl_xor(ss, 16, 64); ss += __shfl_xor(ss, 32, 64);
    float scale = 1.0f / fmaxf(sqrtf(ss), 1e-12f);
    float kn = kv * scale;
    KK[idx] = kn;
    Ab[idx] = kn * Ab[idx];
}

// ---------------------------------------------------------------------------
// Gate stage-2: G = tanh(sum_ks l2p[:,0:128]) @ gate_w2[128,2048]
// ---------------------------------------------------------------------------
__global__ __launch_bounds__(256) void k_gate2(
    const float* __restrict__ l2p, const float* __restrict__ w2, float* __restrict__ G)
{
    const int tid = threadIdx.x;
    const int c = blockIdx.x * 256 + tid;
    const int t0 = blockIdx.y * 16;
    const size_t P = (size_t)T_ * 256;
    __shared__ __align__(16) float gs[16][128];
#pragma unroll
    for (int p = 0; p < 2; ++p) {
        int id = tid + p * 256;
        int r = id >> 5, c4 = (id & 31) * 4;
        size_t off = (size_t)(t0 + r) * 256 + c4;
        float4 v0 = *(const float4*)&l2p[off];
        float4 v1 = *(const float4*)&l2p[P + off];
        float4 v2 = *(const float4*)&l2p[2 * P + off];
        float4 v3 = *(const float4*)&l2p[3 * P + off];
        float4 v;
        v.x = tanhf(((v0.x + v1.x) + v2.x) + v3.x);
        v.y = tanhf(((v0.y + v1.y) + v2.y) + v3.y);
        v.z = tanhf(((v0.z + v1.z) + v2.z) + v3.z);
        v.w = tanhf(((v0.w + v1.w) + v2.w) + v3.w);
        *(float4*)&gs[r][c4] = v;
    }
    __syncthreads();
    float acc[16];
#pragma unroll
    for (int r = 0; r < 16; ++r) acc[r] = 0.f;
    for (int j = 0; j < 128; ++j) {
        float w = w2[(size_t)j * C_ + c];
#pragma unroll
        for (int r = 0; r < 16; ++r) acc[r] = fmaf(gs[r][j], w, acc[r]);
    }
    for (int r = 0; r < 16; ++r) G[(size_t)(t0 + r) * C_ + c] = acc[r];
}

// ---------------------------------------------------------------------------
// WKV7 scan. 4 blocks/head; 256 thr; wave covers 4 rows x 16 j-groups.
// ---------------------------------------------------------------------------
__global__ __launch_bounds__(256) void k_wkv(
    const float* __restrict__ R, const float* __restrict__ Wd,
    const float* __restrict__ K, const float* __restrict__ V,
    const float* __restrict__ KK, const float* __restrict__ Bb,
    float* __restrict__ Y)
{
    const int tid = threadIdx.x;
    const int h = blockIdx.x >> 2;
    const int rg = blockIdx.x & 3;
    const int c0 = h * 64;
    const int wv = tid >> 6, lane = tid & 63;
    const int irow = rg * 16 + wv * 4 + (lane >> 4);
    const int jg = lane & 15;
    __shared__ __align__(16) float rS[16][64], dS[16][64], kS[16][64],
                                   vS[16][64], aS[16][64], bS[16][64], oS[16][64];
    float4 s = make_float4(0.f, 0.f, 0.f, 0.f);
    const int tloc = tid >> 4, j4 = (tid & 15) * 4;

    for (int tc = 0; tc < T_; tc += 16) {
        size_t gi = (size_t)(tc + tloc) * C_ + c0 + j4;
        *(float4*)&rS[tloc][j4] = *(const float4*)&R[gi];
        float4 w4 = *(const float4*)&Wd[gi];
        float4 d4;
        d4.x = __expf(w4.x); d4.y = __expf(w4.y); d4.z = __expf(w4.z); d4.w = __expf(w4.w);
        *(float4*)&dS[tloc][j4] = d4;
        *(float4*)&kS[tloc][j4] = *(const float4*)&K[gi];
        *(float4*)&vS[tloc][j4] = *(const float4*)&V[gi];
        float4 kk4 = *(const float4*)&KK[gi];
        float4 a4 = make_float4(-kk4.x, -kk4.y, -kk4.z, -kk4.w);
        *(float4*)&aS[tloc][j4] = a4;
        *(float4*)&bS[tloc][j4] = *(const float4*)&Bb[gi];
        __syncthreads();

#pragma unroll
        for (int tt = 0; tt < 16; ++tt) {
            float4 a = *(float4*)&aS[tt][jg * 4];
            float sa = s.x * a.x + s.y * a.y + s.z * a.z + s.w * a.w;
            REDUCE16(sa);
            float vi = vS[tt][irow];
            float4 d = *(float4*)&dS[tt][jg * 4];
            float4 b = *(float4*)&bS[tt][jg * 4];
            float4 k = *(float4*)&kS[tt][jg * 4];
            s.x = fmaf(s.x, d.x, fmaf(sa, b.x, vi * k.x));
            s.y = fmaf(s.y, d.y, fmaf(sa, b.y, vi * k.y));
            s.z = fmaf(s.z, d.z, fmaf(sa, b.z, vi * k.z));
            s.w = fmaf(s.w, d.w, fmaf(sa, b.w, vi * k.w));
            float4 r = *(float4*)&rS[tt][jg * 4];
            float o = s.x * r.x + s.y * r.y + s.z * r.z + s.w * r.w;
            REDUCE16(o);
            if (jg == 0) oS[tt][irow] = o;
        }
        __syncthreads();
        Y[(size_t)(tc + tloc) * C_ + c0 + rg * 16 + (tid & 15)] = oS[tloc][rg * 16 + (tid & 15)];
    }
}

// ---------------------------------------------------------------------------
// GroupNorm(y) * ln_w + ln_b, + bonus, * gate -> f16 (A-operand of Wo GEMM)
// ---------------------------------------------------------------------------
__global__ __launch_bounds__(256) void k_gn(
    const float* __restrict__ Y, const float* __restrict__ R, const float* __restrict__ K,
    const float* __restrict__ V, const float* __restrict__ G,
    const float* __restrict__ faaaa, const float* __restrict__ lnw,
    const float* __restrict__ lnb, _Float16* __restrict__ YG)
{
    const int t = blockIdx.y;
    const int c = blockIdx.x * 256 + threadIdx.x;
    const size_t idx = (size_t)t * C_ + c;
    float y = Y[idx];
    float s1 = y, s2 = y * y;
#pragma unroll
    for (int off = 1; off < 64; off <<= 1) {
        s1 += __shfl_xor(s1, off, 64);
        s2 += __shfl_xor(s2, off, 64);
    }
    float mu = s1 * (1.0f / 64.0f);
    float var = s2 * (1.0f / 64.0f) - mu * mu;
    float gn = (y - mu) * rsqrtf(var + 0.00064f) * lnw[c] + lnb[c];
    float p = R[idx] * K[idx] * faaaa[c];
#pragma unroll
    for (int off = 1; off < 64; off <<= 1) p += __shfl_xor(p, off, 64);
    float y2 = gn + p * V[idx];
    YG[idx] = (_Float16)(y2 * G[idx]);
}

// ---------------------------------------------------------------------------
extern "C" void kernel_launch(void* const* d_in, const int* in_sizes, int n_in,
                              void* d_out, int out_size, void* d_ws, size_t ws_size,
                              hipStream_t stream)
{
    (void)in_sizes; (void)n_in; (void)out_size; (void)ws_size;
    const float* hidden   = (const float*)d_in[0];
    const float* Wq       = (const float*)d_in[1];
    const float* Wk       = (const float*)d_in[2];
    const float* Wv       = (const float*)d_in[3];
    const float* Wo       = (const float*)d_in[4];
    const float* maa_x    = (const float*)d_in[5];
    const float* maa_rg   = (const float*)d_in[6];
    const float* maa_wa   = (const float*)d_in[7];
    const float* maa_k    = (const float*)d_in[8];
    const float* maa_v    = (const float*)d_in[9];
    const float* maa_w1   = (const float*)d_in[10];
    const float* maa_w2   = (const float*)d_in[11];
    const float* tdecay   = (const float*)d_in[12];
    const float* decay_w1 = (const float*)d_in[13];
    const float* decay_w2 = (const float*)d_in[14];
    const float* aaaaa    = (const float*)d_in[15];
    const float* aaa_w1   = (const float*)d_in[16];
    const float* aaa_w2   = (const float*)d_in[17];
    const float* kkk_w1   = (const float*)d_in[18];
    const float* kkk_w2   = (const float*)d_in[19];
    const float* gate_w1  = (const float*)d_in[20];
    const float* gate_w2  = (const float*)d_in[21];
    const float* misc_a   = (const float*)d_in[22];
    const float* ma_w1    = (const float*)d_in[23];
    const float* ma_w2    = (const float*)d_in[24];
    const float* misc_k   = (const float*)d_in[25];
    const float* mk_w1    = (const float*)d_in[26];
    const float* mk_w2    = (const float*)d_in[27];
    const float* faaaa    = (const float*)d_in[28];
    const float* lnw      = (const float*)d_in[29];
    const float* lnb      = (const float*)d_in[30];

    float* ws = (float*)d_ws;
    const size_t TC = (size_t)T_ * C_;
    // f32 buffers:
    //   S0: y     S1: g       S2: a_sig -> b    S3: kk
    //   S4: r     S5: w       S6: k0 -> k       S7: v
    float* S0 = ws + 0 * TC;
    float* S1 = ws + 1 * TC;
    float* S2 = ws + 2 * TC;
    float* S3 = ws + 3 * TC;
    float* S4 = ws + 4 * TC;
    float* S5 = ws + 5 * TC;
    float* S6 = ws + 6 * TC;
    float* S7 = ws + 7 * TC;
    float* m1p = ws + 8 * TC;                    // [4][T][128] partials
    float* l2p = m1p + (size_t)4 * T_ * 128;     // [4][T][256] partials
    // f16 region
    _Float16* WTq = (_Float16*)(l2p + (size_t)4 * T_ * 256);
    _Float16* WTk = WTq + (size_t)C_ * C_;
    _Float16* WTv = WTk + (size_t)C_ * C_;
    _Float16* WTo = WTv + (size_t)C_ * C_;
    _Float16* WTm = WTo + (size_t)C_ * C_;       // [128,2048]
    _Float16* WTl = WTm + (size_t)128 * C_;      // [256,2048]
    _Float16* xxxH = WTl + (size_t)256 * C_;
    _Float16* xrgH = xxxH + TC;
    _Float16* xwaH = xrgH + TC;
    _Float16* xkH  = xwaH + TC;
    _Float16* xvH  = xkH + TC;
    _Float16* ygH  = xxxH;                       // xxxH dead after step 4
    float* out = (float*)d_out;

    // 1. transpose+convert big weights
    k_tr<<<dim3(32, 32, 4), 256, 0, stream>>>(Wq, Wk, Wv, Wo, WTq, WTk, WTv, WTo);
    // 2. pack+transpose LoRA weights (z=0: WTm, z=1: WTl)
    k_trW<<<dim3(8, 256, 2), 256, 0, stream>>>(maa_w1, gate_w1, decay_w1,
        aaa_w1, ma_w1, kkk_w1, mk_w1, WTm, WTl);
    // 3. xxxH
    k_prep<<<dim3((int)(TC / 256)), 256, 0, stream>>>(hidden, maa_x, xxxH);
    // 4. m1 partials = xxxH @ WTm^T
    k_lora<<<dim3(16, 4, 4), 256, 0, stream>>>(0, xxxH, xxxH, xxxH, xxxH,
        WTm, WTl, m1p, l2p);
    // 5. xmix -> f16 operands
    k_xmix<<<dim3(8, 64), 256, 0, stream>>>(hidden, m1p, maa_w2,
        maa_rg, maa_wa, maa_k, maa_v, xrgH, xwaH, xkH, xvH);
    // 6. l2 partials (gate | decay | aaa | ma | kkk | mk)
    k_lora<<<dim3(16, 8, 4), 256, 0, stream>>>(1, xxxH, xrgH, xwaH, xkH,
        WTm, WTl, m1p, l2p);
    // 7. r, k0, v (f16 MFMA)
    k_gemm<<<dim3(16, 8, 3), 256, 0, stream>>>(
        xrgH, WTq, S4,  xkH, WTk, S6,  xvH, WTv, S7);
    // 8. fused stage-2: w, kk_un, k_final, a_sig
    k_fuse<<<dim3(8, 64), 256, 0, stream>>>(l2p, S6, decay_w2, aaa_w2, ma_w2,
        kkk_w2, mk_w2, tdecay, aaaaa, misc_a, misc_k, S5, S3, S2);
    // 9. kk normalize + b = kk*a
    k_kknorm<<<dim3(8, 1024), 256, 0, stream>>>(S3, S2);
    // 10. g = tanh(l2 gate) @ gate_w2
    k_gate2<<<dim3(8, 64), 256, 0, stream>>>(l2p, gate_w2, S1);
    // 11. WKV7 scan -> y (S0)
    k_wkv<<<dim3(128), 256, 0, stream>>>(S4, S5, S6, S7, S3, S2, S0);
    // 12. groupnorm + bonus + gate -> f16 (reuses xxxH slot)
    k_gn<<<dim3(8, 1024), 256, 0, stream>>>(S0, S4, S6, S7, S1, faaaa, lnw, lnb, ygH);
    // 13. out = (y*g) @ Wo
    k_gemm<<<dim3(16, 8, 1), 256, 0, stream>>>(
        ygH, WTo, out,  ygH, WTo, out,  ygH, WTo, out);
}